// Round 8
// baseline (581.759 us; speedup 1.0000x reference)
//
#include <hip/hip_runtime.h>

#define BSZ 8
#define TLEN 1024
#define DM 64
#define DI 128
#define DS 32
#define NTOK (BSZ*TLEN)
#define NCHUNK 16
#define CLEN 64
#define GEXT 1028   // 1024 z-tokens + up to 4 predz tokens (global token axis for block-0 buffers)

__device__ __forceinline__ float siluf(float x) { return x / (1.f + expf(-x)); }
__device__ __forceinline__ float softplusf(float x) { return (x > 20.f) ? x : log1pf(expf(x)); }

// ---------------- fused encoder + reconstruction decoder: 8 tokens/block, 1024 blocks ----------------
__global__ __launch_bounds__(256,4) void enc_xrec_kernel(
    const float* __restrict__ x,
    const float* __restrict__ We1, const float* __restrict__ be1,
    const float* __restrict__ We2, const float* __restrict__ be2,
    const float* __restrict__ Wd1, const float* __restrict__ bd1,
    const float* __restrict__ Wd2, const float* __restrict__ bd2,
    float* __restrict__ z, float* __restrict__ x_rec)
{
  __shared__ float s_x[8*32];
  __shared__ float s_h1[8*64];
  __shared__ float s_z[8*64];
  __shared__ float s_h2[8*64];
  const int tid = threadIdx.x;
  const int t0 = blockIdx.x * 8;
  s_x[tid] = x[(size_t)t0*32 + tid];
  __syncthreads();
  const int j = tid & 63, tg = tid >> 6;   // tg 0..3 -> tokens tg*2, tg*2+1
  { // enc stage 1
    float w[32];
    #pragma unroll
    for (int k = 0; k < 32; k++) w[k] = We1[k*64 + j];
    #pragma unroll
    for (int q = 0; q < 2; q++) {
      int t = tg*2 + q;
      float a = be1[j];
      #pragma unroll
      for (int k = 0; k < 32; k++) a = fmaf(s_x[t*32 + k], w[k], a);
      s_h1[t*64 + j] = fmaxf(a, 0.f);
    }
  }
  __syncthreads();
  { // enc stage 2 -> z
    float w[64];
    #pragma unroll
    for (int k = 0; k < 64; k++) w[k] = We2[k*64 + j];
    #pragma unroll
    for (int q = 0; q < 2; q++) {
      int t = tg*2 + q;
      float a = be2[j];
      #pragma unroll
      for (int k = 0; k < 64; k++) a = fmaf(s_h1[t*64 + k], w[k], a);
      s_z[t*64 + j] = a;
      z[(size_t)(t0 + t)*64 + j] = a;
    }
  }
  __syncthreads();
  { // dec stage 1
    float w[64];
    #pragma unroll
    for (int k = 0; k < 64; k++) w[k] = Wd1[k*64 + j];
    #pragma unroll
    for (int q = 0; q < 2; q++) {
      int t = tg*2 + q;
      float a = bd1[j];
      #pragma unroll
      for (int k = 0; k < 64; k++) a = fmaf(s_z[t*64 + k], w[k], a);
      s_h2[t*64 + j] = fmaxf(a, 0.f);
    }
  }
  __syncthreads();
  { // dec stage 2 -> x_rec (8 tok x 32 cols = 256 jobs, 1/thread)
    const int c = tid & 31, t = tid >> 5;
    float a = bd2[c];
    const float4* hh = (const float4*)&s_h2[t*64];
    #pragma unroll
    for (int k4 = 0; k4 < 16; k4++) {
      float4 hv = hh[k4];
      a = fmaf(hv.x, Wd2[(k4*4+0)*32 + c], a);
      a = fmaf(hv.y, Wd2[(k4*4+1)*32 + c], a);
      a = fmaf(hv.z, Wd2[(k4*4+2)*32 + c], a);
      a = fmaf(hv.w, Wd2[(k4*4+3)*32 + c], a);
    }
    x_rec[(size_t)(t0 + t)*32 + c] = a;
  }
}

// ---------------- final decoder: x_dyn = dec(zdyn) [1024 blk] + x_pred = dec(predz) [4 blk] ----
__global__ __launch_bounds__(256,4) void dec2_kernel(
    const float* __restrict__ za, const float* __restrict__ zb,
    const float* __restrict__ W1, const float* __restrict__ b1,
    const float* __restrict__ W2, const float* __restrict__ b2,
    float* __restrict__ outa, float* __restrict__ outb)
{
  __shared__ float s_z[8*64];
  __shared__ float s_h[8*64];
  const int tid = threadIdx.x;
  const float* src; float* dst; int t0;
  if (blockIdx.x < 1024) { src = za; dst = outa; t0 = blockIdx.x * 8; }
  else                   { src = zb; dst = outb; t0 = (blockIdx.x - 1024) * 8; }
  s_z[tid]       = src[(size_t)t0*64 + tid];
  s_z[tid + 256] = src[(size_t)t0*64 + tid + 256];
  __syncthreads();
  const int j = tid & 63, tg = tid >> 6;
  {
    float w[64];
    #pragma unroll
    for (int k = 0; k < 64; k++) w[k] = W1[k*64 + j];
    #pragma unroll
    for (int q = 0; q < 2; q++) {
      int t = tg*2 + q;
      float a = b1[j];
      #pragma unroll
      for (int k = 0; k < 64; k++) a = fmaf(s_z[t*64 + k], w[k], a);
      s_h[t*64 + j] = fmaxf(a, 0.f);
    }
  }
  __syncthreads();
  {
    const int c = tid & 31, t = tid >> 5;
    float a = b2[c];
    const float4* hh = (const float4*)&s_h[t*64];
    #pragma unroll
    for (int k4 = 0; k4 < 16; k4++) {
      float4 hv = hh[k4];
      a = fmaf(hv.x, W2[(k4*4+0)*32 + c], a);
      a = fmaf(hv.y, W2[(k4*4+1)*32 + c], a);
      a = fmaf(hv.z, W2[(k4*4+2)*32 + c], a);
      a = fmaf(hv.w, W2[(k4*4+3)*32 + c], a);
    }
    dst[(size_t)(t0 + t)*32 + c] = a;
  }
}

// ---------------- pre: 4 tokens/block (+3 halo), 2048 blocks, 32 waves/CU ----------------
__global__ __launch_bounds__(256,8) void pre_kernel(
    const float* __restrict__ inbuf, const float* __restrict__ zsrc, const float* __restrict__ pzsrc, int shift,
    const float* __restrict__ Win, const float* __restrict__ Wconv, const float* __restrict__ bconv,
    const float* __restrict__ Wxproj, const float* __restrict__ Wdt, const float* __restrict__ bdt,
    float* __restrict__ xibuf, float* __restrict__ resgbuf,
    float2* __restrict__ ddbuf, float* __restrict__ Bbuf, float* __restrict__ Cbuf,
    float* __restrict__ xzout, int wstride)
{
  __shared__ float s_xi[4*128];
  __shared__ float s_dtr[4*4];
  const int tid = threadIdx.x;
  const int b  = blockIdx.x >> 8;
  const int t0 = (blockIdx.x & 255) * 4;

  const float* rowp[7];
  #pragma unroll
  for (int r = 0; r < 7; r++) {
    int tg = t0 - 3 + r;
    const float* rp = inbuf;
    if (tg >= 0) {
      if (zsrc) {
        int st = tg + shift;
        rp = (st < TLEN) ? zsrc + (size_t)(b*TLEN + st)*DM
                         : pzsrc + (size_t)(b*4 + (st - TLEN))*DM;
      } else {
        rp = inbuf + (size_t)(b*TLEN + tg)*DM;
      }
    }
    rowp[r] = rp;
  }

  float acc[7];
  #pragma unroll
  for (int r = 0; r < 7; r++) acc[r] = 0.f;

  if (t0 > 0) {
    #pragma unroll
    for (int k4 = 0; k4 < 16; k4++) {
      float w0 = Win[(k4*4+0)*256 + tid];
      float w1 = Win[(k4*4+1)*256 + tid];
      float w2 = Win[(k4*4+2)*256 + tid];
      float w3 = Win[(k4*4+3)*256 + tid];
      #pragma unroll
      for (int r = 0; r < 7; r++) {
        float4 xv = *(const float4*)(rowp[r] + k4*4);
        acc[r] = fmaf(xv.x, w0, acc[r]);
        acc[r] = fmaf(xv.y, w1, acc[r]);
        acc[r] = fmaf(xv.z, w2, acc[r]);
        acc[r] = fmaf(xv.w, w3, acc[r]);
      }
    }
  } else {
    #pragma unroll
    for (int k4 = 0; k4 < 16; k4++) {
      float w0 = Win[(k4*4+0)*256 + tid];
      float w1 = Win[(k4*4+1)*256 + tid];
      float w2 = Win[(k4*4+2)*256 + tid];
      float w3 = Win[(k4*4+3)*256 + tid];
      #pragma unroll
      for (int r = 3; r < 7; r++) {
        float4 xv = *(const float4*)(rowp[r] + k4*4);
        acc[r] = fmaf(xv.x, w0, acc[r]);
        acc[r] = fmaf(xv.y, w1, acc[r]);
        acc[r] = fmaf(xv.z, w2, acc[r]);
        acc[r] = fmaf(xv.w, w3, acc[r]);
      }
    }
  }

  if (tid < 128) {
    float4 wc = *(const float4*)&Wconv[tid*4];
    float bc = bconv[tid];
    #pragma unroll
    for (int tau = 0; tau < 4; tau++) {
      float v = bc;
      v = fmaf(acc[tau+0], wc.x, v);
      v = fmaf(acc[tau+1], wc.y, v);
      v = fmaf(acc[tau+2], wc.z, v);
      v = fmaf(acc[tau+3], wc.w, v);
      float xiv = siluf(v);
      s_xi[tau*128 + tid] = xiv;
      xibuf[((size_t)b*wstride + t0 + tau)*DI + tid] = xiv;
      if (xzout) xzout[((size_t)b*wstride + t0 + tau)*128 + tid] = acc[tau+3];
    }
  } else {
    int d = tid - 128;
    #pragma unroll
    for (int tau = 0; tau < 4; tau++)
      resgbuf[((size_t)b*wstride + t0 + tau)*DI + d] = siluf(acc[tau+3]);
  }
  __syncthreads();
  // xproj B/C cols: wave wv -> token wv; lane c -> proj col 4+c
  {
    const int wv = tid >> 6, c = tid & 63;
    float a0 = 0.f;
    const float4* x0 = (const float4*)&s_xi[wv*128];
    #pragma unroll 8
    for (int k4 = 0; k4 < 32; k4++) {
      float4 v0 = x0[k4];
      a0 = fmaf(v0.x, Wxproj[(k4*4+0)*68 + 4 + c],
           fmaf(v0.y, Wxproj[(k4*4+1)*68 + 4 + c],
           fmaf(v0.z, Wxproj[(k4*4+2)*68 + 4 + c],
           fmaf(v0.w, Wxproj[(k4*4+3)*68 + 4 + c], a0))));
    }
    size_t tb = (size_t)b*wstride + t0 + wv;
    if (c < 32) Bbuf[tb*DS + c] = a0;
    else        Cbuf[tb*DS + (c-32)] = a0;
  }
  // dtr cols (4 per token), threads 0..15
  if (tid < 16) {
    int tau = tid >> 2, cc = tid & 3;
    float a = 0.f;
    const float4* xx = (const float4*)&s_xi[tau*128];
    #pragma unroll 8
    for (int k4 = 0; k4 < 32; k4++) {
      float4 v = xx[k4];
      a = fmaf(v.x, Wxproj[(k4*4+0)*68 + cc], a);
      a = fmaf(v.y, Wxproj[(k4*4+1)*68 + cc], a);
      a = fmaf(v.z, Wxproj[(k4*4+2)*68 + cc], a);
      a = fmaf(v.w, Wxproj[(k4*4+3)*68 + cc], a);
    }
    s_dtr[tau*4 + cc] = a;
  }
  __syncthreads();
  // dt = softplus(dtr @ Wdt + bdt); dd = (dt, dt*xi)  (4x128 = 512 jobs)
  #pragma unroll
  for (int u = 0; u < 2; u++) {
    int i = tid + u*256;
    int tau = i >> 7, d = i & 127;
    float a = bdt[d];
    #pragma unroll
    for (int r = 0; r < 4; r++) a = fmaf(s_dtr[tau*4 + r], Wdt[r*128 + d], a);
    float dtv = softplusf(a);
    ddbuf[((size_t)b*wstride + t0 + tau)*DI + d] = make_float2(dtv, dtv * s_xi[i]);
  }
}

// B/C chunk swizzle (r4): breaks the stride-68 8-way conflict down to <=2-way.
#define BSWZ(row3) (((row3)&3)<<1)

// ---------------- scan phase 1: per-chunk summary (hend, hdec) via group-anchored sums ----------------
// No long exp->fma chain: per 8-step group all terms are independent exp(A*(c8-ct))*u with
// exponents <= 0; groups fold with an 8-deep fma chain.
__global__ __launch_bounds__(128,8) void scan1_kernel(
    const float2* __restrict__ ddbuf, const float* __restrict__ Bbuf,
    const float* __restrict__ Alog, float2* __restrict__ hc, int stride, int off)
{
  __shared__ float2 s_dd[4][CLEN];
  __shared__ float  s_Bt[32][68];
  const int tid = threadIdx.x;
  const int ch = tid >> 5, s = tid & 31;
  const int dg = blockIdx.x & 31;
  const int c  = (blockIdx.x >> 5) & 15;
  const int b  = blockIdx.x >> 9;
  const int d0 = dg * 4;
  const float A = -__expf(Alog[(d0 + ch)*DS + s]);
  const float2* ddg = ddbuf + ((size_t)b*stride + off + c*CLEN)*DI + d0;
  const float*  Bg  = Bbuf  + ((size_t)b*stride + off + c*CLEN)*DS;
  {
    int t = tid >> 1, half = tid & 1;
    float4 rdd = *(const float4*)((const float*)(ddg + (size_t)t*DI) + half*4);
    s_dd[2*half+0][t] = make_float2(rdd.x, rdd.y);
    s_dd[2*half+1][t] = make_float2(rdd.z, rdd.w);
    #pragma unroll
    for (int j = 0; j < 4; j++) {
      int q = tid + 128*j; int tt = q >> 3, k4 = q & 7;
      float4 rB = *(const float4*)(Bg + tt*DS + k4*4);
      int cp = (((tt>>2) ^ BSWZ(k4>>1)) << 2) + (tt & 3);
      s_Bt[k4*4+0][cp] = rB.x; s_Bt[k4*4+1][cp] = rB.y;
      s_Bt[k4*4+2][cp] = rB.z; s_Bt[k4*4+3][cp] = rB.w;
    }
  }
  __syncthreads();
  const float4* dd4 = (const float4*)&s_dd[ch][0];
  const float4* bt4 = (const float4*)&s_Bt[s][0];
  const int swr = BSWZ(s>>3);
  float h = 0.f, dectot = 1.f;
  #pragma unroll
  for (int j = 0; j < 8; j++) {
    float4 e0 = dd4[4*j+0], e1 = dd4[4*j+1], e2 = dd4[4*j+2], e3 = dd4[4*j+3];
    float4 bb0 = bt4[(2*j)^swr], bb1 = bt4[(2*j+1)^swr];
    // inclusive dt prefixes within group
    float c1 = e0.x;
    float c2 = c1 + e0.z;
    float c3 = c2 + e1.x;
    float c4 = c3 + e1.z;
    float c5 = c4 + e2.x;
    float c6 = c5 + e2.z;
    float c7 = c6 + e3.x;
    float c8 = c7 + e3.z;
    float gl;
    gl  = e0.y*bb0.x*__expf(A*(c8 - c1));
    gl += e0.w*bb0.y*__expf(A*(c8 - c2));
    gl += e1.y*bb0.z*__expf(A*(c8 - c3));
    gl += e1.w*bb0.w*__expf(A*(c8 - c4));
    gl += e2.y*bb1.x*__expf(A*(c8 - c5));
    gl += e2.w*bb1.y*__expf(A*(c8 - c6));
    gl += e3.y*bb1.z*__expf(A*(c8 - c7));
    gl += e3.w*bb1.w;
    float gdec = __expf(A*c8);
    h = fmaf(gdec, h, gl);
    dectot *= gdec;
  }
  int o = ((b*NCHUNK + c)*DI + d0 + ch)*DS + s;
  hc[o] = make_float2(h, dectot);
}

// ---------------- scan phase 3: prefix-combine + rescan chunk, emit y ----------------
__global__ __launch_bounds__(128) void scan3_kernel(
    const float2* __restrict__ ddbuf, const float* __restrict__ Bbuf, const float* __restrict__ Cbuf,
    const float* __restrict__ Alog, const float2* __restrict__ hc, float* __restrict__ ysbuf,
    int stride, int off)
{
  __shared__ float2 s_dd[4][CLEN];
  __shared__ float  s_Bt[32][68];
  __shared__ float  s_Ct[32][68];
  __shared__ float  s_p[128][33];
  const int tid = threadIdx.x;
  const int ch = tid >> 5, s = tid & 31;
  const int dg = blockIdx.x & 31;
  const int c  = (blockIdx.x >> 5) & 15;
  const int b  = blockIdx.x >> 9;
  const int d0 = dg * 4;
  const float A = -__expf(Alog[(d0 + ch)*DS + s]);
  const float2* ddg = ddbuf + ((size_t)b*stride + off + c*CLEN)*DI + d0;
  const float*  Bg  = Bbuf  + ((size_t)b*stride + off + c*CLEN)*DS;
  const float*  Cg  = Cbuf  + ((size_t)b*stride + off + c*CLEN)*DS;

  const int ob = (d0 + ch)*DS + s;
  float2 v[15];
  #pragma unroll
  for (int q = 0; q < 15; q++) v[q] = hc[(size_t)(b*NCHUNK + q)*4096 + ob];

  {
    int t = tid >> 1, half = tid & 1;
    float4 rdd = *(const float4*)((const float*)(ddg + (size_t)t*DI) + half*4);
    s_dd[2*half+0][t] = make_float2(rdd.x, rdd.y);
    s_dd[2*half+1][t] = make_float2(rdd.z, rdd.w);
    #pragma unroll
    for (int j = 0; j < 4; j++) {
      int q = tid + 128*j; int tt = q >> 3, k4 = q & 7;
      float4 rB = *(const float4*)(Bg + tt*DS + k4*4);
      float4 rC = *(const float4*)(Cg + tt*DS + k4*4);
      int cp = (((tt>>2) ^ BSWZ(k4>>1)) << 2) + (tt & 3);
      s_Bt[k4*4+0][cp] = rB.x; s_Bt[k4*4+1][cp] = rB.y;
      s_Bt[k4*4+2][cp] = rB.z; s_Bt[k4*4+3][cp] = rB.w;
      s_Ct[k4*4+0][cp] = rC.x; s_Ct[k4*4+1][cp] = rC.y;
      s_Ct[k4*4+2][cp] = rC.z; s_Ct[k4*4+3][cp] = rC.w;
    }
  }
  float h = 0.f;
  #pragma unroll
  for (int q = 0; q < 15; q++)
    if (q < c) h = fmaf(v[q].y, h, v[q].x);
  __syncthreads();

  const float4* dd4 = (const float4*)&s_dd[ch][0];
  const float4* bt4 = (const float4*)&s_Bt[s][0];
  const float4* ct4 = (const float4*)&s_Ct[s][0];
  const int swr = BSWZ(s>>3);
  float* pr = &s_p[tid][0];
  #pragma unroll
  for (int half = 0; half < 2; half++) {
    #pragma unroll
    for (int j = 0; j < 4; j++) {
      const int jj = half*4 + j;
      float4 e0 = dd4[4*jj+0], e1 = dd4[4*jj+1], e2 = dd4[4*jj+2], e3 = dd4[4*jj+3];
      float4 bb0 = bt4[(2*jj)^swr], bb1 = bt4[(2*jj+1)^swr];
      float4 cc0 = ct4[(2*jj)^swr], cc1 = ct4[(2*jj+1)^swr];
      h = fmaf(__expf(e0.x*A), h, e0.y*bb0.x); pr[8*j+0] = h*cc0.x;
      h = fmaf(__expf(e0.z*A), h, e0.w*bb0.y); pr[8*j+1] = h*cc0.y;
      h = fmaf(__expf(e1.x*A), h, e1.y*bb0.z); pr[8*j+2] = h*cc0.z;
      h = fmaf(__expf(e1.z*A), h, e1.w*bb0.w); pr[8*j+3] = h*cc0.w;
      h = fmaf(__expf(e2.x*A), h, e2.y*bb1.x); pr[8*j+4] = h*cc1.x;
      h = fmaf(__expf(e2.z*A), h, e2.w*bb1.y); pr[8*j+5] = h*cc1.y;
      h = fmaf(__expf(e3.x*A), h, e3.y*bb1.z); pr[8*j+6] = h*cc1.z;
      h = fmaf(__expf(e3.z*A), h, e3.w*bb1.w); pr[8*j+7] = h*cc1.w;
    }
    __syncthreads();
    {
      const int ch2 = tid & 3;
      const int tq  = tid >> 2;
      float a = 0.f;
      #pragma unroll
      for (int s2 = 0; s2 < 32; s2++) a += s_p[ch2*32 + s2][tq];
      ysbuf[(size_t)(b*TLEN + c*CLEN + half*32 + tq)*DI + d0 + ch2] = a;
    }
    __syncthreads();
  }
}

// ---------------- post: 4 tokens/block, 2048 blocks ----------------
__global__ __launch_bounds__(256,8) void post_kernel(
    const float* __restrict__ ysbuf, const float* __restrict__ xibuf, const float* __restrict__ resgbuf,
    const float* __restrict__ Dp, const float* __restrict__ Wout,
    const float* __restrict__ zsrc, const float* __restrict__ pzsrc, int shift,
    float* __restrict__ outbuf, float* __restrict__ zdyn, float* __restrict__ predz,
    const float* __restrict__ gamma, const float* __restrict__ beta, int mode,
    int rstride, int roff)
{
  __shared__ float s_y[4*128];
  const int tid = threadIdx.x;
  const int b  = blockIdx.x >> 8;
  const int t0 = (blockIdx.x & 255) * 4;
  #pragma unroll
  for (int u = 0; u < 2; u++) {
    int i = tid + u*256;
    size_t gy = (size_t)(b*TLEN + t0)*DI + i;
    size_t gx = ((size_t)b*rstride + roff + t0)*DI + i;
    s_y[i] = (ysbuf[gy] + xibuf[gx]*Dp[i & 127]) * resgbuf[gx];
  }
  __syncthreads();
  {
    const int tau = tid >> 6, c = tid & 63;
    float a = 0.f;
    const float4* yy = (const float4*)&s_y[tau*128];
    #pragma unroll 8
    for (int k4 = 0; k4 < 32; k4++) {
      float4 vv = yy[k4];
      a = fmaf(vv.x, Wout[(k4*4+0)*64 + c], a);
      a = fmaf(vv.y, Wout[(k4*4+1)*64 + c], a);
      a = fmaf(vv.z, Wout[(k4*4+2)*64 + c], a);
      a = fmaf(vv.w, Wout[(k4*4+3)*64 + c], a);
    }
    size_t g = (size_t)(b*TLEN + t0 + tau)*DM + c;
    float base;
    if (zsrc) {
      int st = t0 + tau + shift;
      base = (st < TLEN) ? zsrc[(size_t)(b*TLEN + st)*DM + c] : pzsrc[(size_t)(b*4 + (st - TLEN))*DM + c];
    } else {
      base = outbuf[g];
    }
    float val = base + a;
    if (mode == 0) {
      outbuf[g] = val;
    } else {
      float sum = val;
      #pragma unroll
      for (int m = 1; m < 64; m <<= 1) sum += __shfl_xor(sum, m);
      float mean = sum * (1.f/64.f);
      float dv = val - mean;
      float vs = dv*dv;
      #pragma unroll
      for (int m = 1; m < 64; m <<= 1) vs += __shfl_xor(vs, m);
      float oln = dv * rsqrtf(vs*(1.f/64.f) + 1e-5f) * gamma[c] + beta[c];
      zdyn[g] = oln;
      if (t0 + tau == TLEN-1) predz[(size_t)(b*4 + 0)*DM + c] = oln;
    }
  }
}

// ---------------- patch: [fold i1 summaries -> predz[p-1]] + recompute pre(i0) for
// tokens {p, p+1, p+2, 1023+p}. 8 blocks, 256 threads. only_tp: fold only (finish).
__global__ __launch_bounds__(256) void patch_kernel(
    int p, int do_tp, int only_tp,
    const float2* __restrict__ hc1, const float* __restrict__ Cb1, const float* __restrict__ cur,
    const float* __restrict__ xi1, const float* __restrict__ resg1,
    const float* __restrict__ Dp1, const float* __restrict__ Wout1,
    const float* __restrict__ gamma, const float* __restrict__ beta,
    float* __restrict__ predz,
    float* __restrict__ xz0,
    const float* __restrict__ Win0, const float* __restrict__ Wconv0, const float* __restrict__ bconv0,
    const float* __restrict__ Wxp0, const float* __restrict__ Wdt0, const float* __restrict__ bdt0,
    float* __restrict__ xi0, float* __restrict__ resg0,
    float2* __restrict__ dd0, float* __restrict__ Bb0, float* __restrict__ Cb0)
{
  __shared__ float s_pz[64];
  __shared__ float s_part[2][128];
  __shared__ float s_y[128];
  __shared__ float s_new[256];
  __shared__ float s_xi[4][128];
  __shared__ float s_dtr[4][4];
  const int tid = threadIdx.x;
  const int b = blockIdx.x;
  const int gn = 1023 + p;

  if (do_tp) {
    // fold 16 chunk summaries of block-1 (prev pass) -> h_final; y_last = C[1023] . h_final
    {
      const int d = tid & 127, sh = tid >> 7;
      float yp = 0.f;
      #pragma unroll
      for (int s2 = 0; s2 < 16; s2++) {
        int s = sh*16 + s2;
        float h = 0.f;
        #pragma unroll
        for (int cc = 0; cc < 16; cc++) {
          float2 v = hc1[((size_t)(b*NCHUNK + cc)*DI + d)*DS + s];
          h = fmaf(v.y, h, v.x);
        }
        yp = fmaf(Cb1[(size_t)(b*TLEN + TLEN-1)*DS + s], h, yp);
      }
      s_part[sh][d] = yp;
    }
    __syncthreads();
    if (tid < 128) {
      size_t g = (size_t)(b*TLEN + TLEN-1)*DI + tid;
      s_y[tid] = ((s_part[0][tid] + s_part[1][tid]) + xi1[g]*Dp1[tid]) * resg1[g];
    }
    __syncthreads();
    if (tid < 64) {
      float a = 0.f;
      #pragma unroll 4
      for (int k = 0; k < 128; k++) a = fmaf(s_y[k], Wout1[k*64 + tid], a);
      float val = cur[(size_t)(b*TLEN + TLEN-1)*DM + tid] + a;
      float sum = val;
      #pragma unroll
      for (int m = 1; m < 64; m <<= 1) sum += __shfl_xor(sum, m);
      float mean = sum * (1.f/64.f);
      float dv = val - mean;
      float vs = dv*dv;
      #pragma unroll
      for (int m = 1; m < 64; m <<= 1) vs += __shfl_xor(vs, m);
      float oln = dv * rsqrtf(vs*(1.f/64.f) + 1e-5f) * gamma[tid] + beta[tid];
      predz[(size_t)(b*4 + p-1)*DM + tid] = oln;
      s_pz[tid] = oln;
    }
  } else {
    if (tid < 64) s_pz[tid] = predz[(size_t)(b*4 + p-1)*DM + tid];
  }
  __syncthreads();
  if (only_tp) return;

  // phase 1: xz of the new token gn
  {
    float a = 0.f;
    #pragma unroll
    for (int k = 0; k < 64; k++) a = fmaf(s_pz[k], Win0[k*256 + tid], a);
    s_new[tid] = a;
  }
  __syncthreads();
  if (tid < 128) xz0[((size_t)b*GEXT + gn)*128 + tid] = s_new[tid];
  else           resg0[((size_t)b*GEXT + gn)*DI + (tid-128)] = siluf(s_new[tid]);

  // phase 2: conv + silu for 4 tokens x 128 ch
  #pragma unroll
  for (int jj = 0; jj < 2; jj++) {
    int job = tid + jj*256;
    int tok = job >> 7, d = job & 127;
    int g = (tok < 3) ? (p + tok) : gn;
    float a = bconv0[d];
    #pragma unroll
    for (int k = 0; k < 4; k++) {
      int row = g - 3 + k;
      float xv;
      if (tok < 3) xv = (row >= p) ? xz0[((size_t)b*GEXT + row)*128 + d] : 0.f;
      else         xv = (k < 3) ? xz0[((size_t)b*GEXT + row)*128 + d] : s_new[d];
      a = fmaf(xv, Wconv0[d*4 + k], a);
    }
    float xiv = siluf(a);
    s_xi[tok][d] = xiv;
    xi0[((size_t)b*GEXT + g)*DI + d] = xiv;
  }
  __syncthreads();

  // phase 3: xproj: 4 tokens x 68 cols = 272 jobs
  #pragma unroll
  for (int jj = 0; jj < 2; jj++) {
    int job = tid + jj*256;
    if (job < 272) {
      int tok = job / 68, c = job % 68;
      int g = (tok < 3) ? (p + tok) : gn;
      float a = 0.f;
      #pragma unroll 4
      for (int k = 0; k < 128; k++) a = fmaf(s_xi[tok][k], Wxp0[k*68 + c], a);
      if (c < 4)        s_dtr[tok][c] = a;
      else if (c < 36)  Bb0[((size_t)b*GEXT + g)*DS + (c - 4)]  = a;
      else              Cb0[((size_t)b*GEXT + g)*DS + (c - 36)] = a;
    }
  }
  __syncthreads();

  // phase 4: dt + dd
  #pragma unroll
  for (int jj = 0; jj < 2; jj++) {
    int job = tid + jj*256;
    int tok = job >> 7, d = job & 127;
    int g = (tok < 3) ? (p + tok) : gn;
    float a = bdt0[d];
    #pragma unroll
    for (int r = 0; r < 4; r++) a = fmaf(s_dtr[tok][r], Wdt0[r*128 + d], a);
    float dtv = softplusf(a);
    dd0[((size_t)b*GEXT + g)*DI + d] = make_float2(dtv, dtv * s_xi[tok][d]);
  }
}

extern "C" void kernel_launch(void* const* d_in, const int* in_sizes, int n_in,
                              void* d_out, int out_size, void* d_ws, size_t ws_size,
                              hipStream_t stream)
{
  (void)in_sizes; (void)n_in; (void)out_size; (void)ws_size;
  const float* x     = (const float*)d_in[0];
  const float* We1   = (const float*)d_in[1];
  const float* be1   = (const float*)d_in[2];
  const float* We2   = (const float*)d_in[3];
  const float* be2   = (const float*)d_in[4];
  const float* Wd1   = (const float*)d_in[5];
  const float* bd1   = (const float*)d_in[6];
  const float* Wd2   = (const float*)d_in[7];
  const float* bd2   = (const float*)d_in[8];
  const float* Win   = (const float*)d_in[9];
  const float* Wconv = (const float*)d_in[10];
  const float* bconv = (const float*)d_in[11];
  const float* Wxp   = (const float*)d_in[12];
  const float* Wdt   = (const float*)d_in[13];
  const float* bdt   = (const float*)d_in[14];
  const float* Alog  = (const float*)d_in[15];
  const float* Dp    = (const float*)d_in[16];
  const float* Wout  = (const float*)d_in[17];
  const float* gamma = (const float*)d_in[18];
  const float* beta  = (const float*)d_in[19];

  float* o      = (float*)d_out;
  float* x_rec  = o;                 // 8*1024*32
  float* x_dyn  = o + 262144;        // 8*1024*32
  float* x_pred = o + 524288;        // 8*4*32
  float* z      = o + 525312;        // 8*1024*64
  float* zdyn   = o + 1049600;       // 8*1024*64

  float* w     = (float*)d_ws;
  float* cur   = w;                            // 524288
  float* xi1   = cur  + 524288;                // 1048576
  float* resg1 = xi1  + 1048576;               // 1048576
  float2* dd1  = (float2*)(resg1 + 1048576);   // 2097152 floats
  float* Bb1   = resg1 + 1048576 + 2097152;    // 262144
  float* Cb1   = Bb1  + 262144;                // 262144
  float* ys    = Cb1  + 262144;                // 1048576
  float2* hc   = (float2*)(ys + 1048576);      // 1048576 floats
  float* predz = ys + 1048576 + 1048576;       // 2048
  float* xi0   = predz + 2048;                 // 1052672 (8*1028*128)
  float* resg0 = xi0  + 1052672;               // 1052672
  float2* dd0  = (float2*)(resg0 + 1052672);   // 2105344 floats
  float* Bb0   = resg0 + 1052672 + 2105344;    // 263168 (8*1028*32)
  float* Cb0   = Bb0  + 263168;                // 263168
  float* xz0   = Cb0  + 263168;                // 1052672

  const float* Win0 = Win,   *Win1 = Win + 64*256;
  const float* Wcv0 = Wconv, *Wcv1 = Wconv + 128*4;
  const float* bcv0 = bconv, *bcv1 = bconv + 128;
  const float* Wxp0 = Wxp,   *Wxp1 = Wxp + 128*68;
  const float* Wdt0 = Wdt,   *Wdt1 = Wdt + 4*128;
  const float* bdt0 = bdt,   *bdt1 = bdt + 128;
  const float* Al0  = Alog,  *Al1  = Alog + 128*32;
  const float* Dp0  = Dp,    *Dp1  = Dp + 128;
  const float* Wo0  = Wout,  *Wo1  = Wout + 128*64;

  // encoder + reconstruction decoder (fused)
  enc_xrec_kernel<<<dim3(1024), dim3(256), 0, stream>>>(x, We1, be1, We2, be2, Wd1, bd1, Wd2, bd2, z, x_rec);

  // pre(i=0) ONCE over global z tokens, storing xz xi-half
  pre_kernel<<<dim3(2048), dim3(256), 0, stream>>>(cur, z, predz, 0,
                                                   Win0, Wcv0, bcv0, Wxp0, Wdt0, bdt0,
                                                   xi0, resg0, dd0, Bb0, Cb0, xz0, GEXT);

  for (int p = 0; p < 4; p++) {
    if (p >= 1) {
      patch_kernel<<<dim3(8), dim3(256), 0, stream>>>(p, (p >= 2) ? 1 : 0, 0,
          hc, Cb1, cur, xi1, resg1, Dp1, Wo1, gamma, beta, predz,
          xz0, Win0, Wcv0, bcv0, Wxp0, Wdt0, bdt0,
          xi0, resg0, dd0, Bb0, Cb0);
    }
    // ---- block i=0 (shared pre buffers, window at offset p) ----
    scan1_kernel<<<dim3(4096), dim3(128), 0, stream>>>(dd0, Bb0, Al0, hc, GEXT, p);
    scan3_kernel<<<dim3(4096), dim3(128), 0, stream>>>(dd0, Bb0, Cb0, Al0, hc, ys, GEXT, p);
    post_kernel<<<dim3(2048), dim3(256), 0, stream>>>(ys, xi0, resg0, Dp0, Wo0,
                                                      z, predz, p, cur,
                                                      (float*)nullptr, (float*)nullptr,
                                                      (const float*)nullptr, (const float*)nullptr, 0,
                                                      GEXT, p);
    // ---- block i=1 (pass-local) ----
    pre_kernel<<<dim3(2048), dim3(256), 0, stream>>>(cur, (const float*)nullptr, (const float*)nullptr, 0,
                                                     Win1, Wcv1, bcv1, Wxp1, Wdt1, bdt1,
                                                     xi1, resg1, dd1, Bb1, Cb1, (float*)nullptr, TLEN);
    scan1_kernel<<<dim3(4096), dim3(128), 0, stream>>>(dd1, Bb1, Al1, hc, TLEN, 0);
    if (p == 0) {
      scan3_kernel<<<dim3(4096), dim3(128), 0, stream>>>(dd1, Bb1, Cb1, Al1, hc, ys, TLEN, 0);
      post_kernel<<<dim3(2048), dim3(256), 0, stream>>>(ys, xi1, resg1, Dp1, Wo1,
                                                        (const float*)nullptr, (const float*)nullptr, 0, cur,
                                                        zdyn, predz, gamma, beta, 1, TLEN, 0);
    }
    // p>=1: block-1 last-token output is folded from hc by the next patch / finish.
  }

  // finish: predz[3] from pass-3 block-1 summaries
  patch_kernel<<<dim3(8), dim3(256), 0, stream>>>(4, 1, 1,
      hc, Cb1, cur, xi1, resg1, Dp1, Wo1, gamma, beta, predz,
      xz0, Win0, Wcv0, bcv0, Wxp0, Wdt0, bdt0,
      xi0, resg0, dd0, Bb0, Cb0);

  // x_dyn = dec(zdyn) + x_pred = dec(predz)
  dec2_kernel<<<dim3(1028), dim3(256), 0, stream>>>(zdyn, predz, Wd1, bd1, Wd2, bd2, x_dyn, x_pred);
}

// Round 9
// 546.094 us; speedup vs baseline: 1.0653x; 1.0653x over previous
//
#include <hip/hip_runtime.h>

#define BSZ 8
#define TLEN 1024
#define DM 64
#define DI 128
#define DS 32
#define NTOK (BSZ*TLEN)
#define NCHUNK 16
#define CLEN 64
#define GEXT 1028   // 1024 z-tokens + up to 4 predz tokens (global token axis for block-0 buffers)

__device__ __forceinline__ float siluf(float x) { return x / (1.f + expf(-x)); }
__device__ __forceinline__ float softplusf(float x) { return (x > 20.f) ? x : log1pf(expf(x)); }

// ---------------- fused encoder + reconstruction decoder: 8 tokens/block, 1024 blocks ----------------
__global__ __launch_bounds__(256,4) void enc_xrec_kernel(
    const float* __restrict__ x,
    const float* __restrict__ We1, const float* __restrict__ be1,
    const float* __restrict__ We2, const float* __restrict__ be2,
    const float* __restrict__ Wd1, const float* __restrict__ bd1,
    const float* __restrict__ Wd2, const float* __restrict__ bd2,
    float* __restrict__ z, float* __restrict__ x_rec)
{
  __shared__ float s_x[8*32];
  __shared__ float s_h1[8*64];
  __shared__ float s_z[8*64];
  __shared__ float s_h2[8*64];
  const int tid = threadIdx.x;
  const int t0 = blockIdx.x * 8;
  s_x[tid] = x[(size_t)t0*32 + tid];
  __syncthreads();
  const int j = tid & 63, tg = tid >> 6;
  { // enc stage 1
    float w[32];
    #pragma unroll
    for (int k = 0; k < 32; k++) w[k] = We1[k*64 + j];
    #pragma unroll
    for (int q = 0; q < 2; q++) {
      int t = tg*2 + q;
      float a = be1[j];
      #pragma unroll
      for (int k = 0; k < 32; k++) a = fmaf(s_x[t*32 + k], w[k], a);
      s_h1[t*64 + j] = fmaxf(a, 0.f);
    }
  }
  __syncthreads();
  { // enc stage 2 -> z
    float w[64];
    #pragma unroll
    for (int k = 0; k < 64; k++) w[k] = We2[k*64 + j];
    #pragma unroll
    for (int q = 0; q < 2; q++) {
      int t = tg*2 + q;
      float a = be2[j];
      #pragma unroll
      for (int k = 0; k < 64; k++) a = fmaf(s_h1[t*64 + k], w[k], a);
      s_z[t*64 + j] = a;
      z[(size_t)(t0 + t)*64 + j] = a;
    }
  }
  __syncthreads();
  { // dec stage 1
    float w[64];
    #pragma unroll
    for (int k = 0; k < 64; k++) w[k] = Wd1[k*64 + j];
    #pragma unroll
    for (int q = 0; q < 2; q++) {
      int t = tg*2 + q;
      float a = bd1[j];
      #pragma unroll
      for (int k = 0; k < 64; k++) a = fmaf(s_z[t*64 + k], w[k], a);
      s_h2[t*64 + j] = fmaxf(a, 0.f);
    }
  }
  __syncthreads();
  { // dec stage 2 -> x_rec
    const int c = tid & 31, t = tid >> 5;
    float a = bd2[c];
    const float4* hh = (const float4*)&s_h2[t*64];
    #pragma unroll
    for (int k4 = 0; k4 < 16; k4++) {
      float4 hv = hh[k4];
      a = fmaf(hv.x, Wd2[(k4*4+0)*32 + c], a);
      a = fmaf(hv.y, Wd2[(k4*4+1)*32 + c], a);
      a = fmaf(hv.z, Wd2[(k4*4+2)*32 + c], a);
      a = fmaf(hv.w, Wd2[(k4*4+3)*32 + c], a);
    }
    x_rec[(size_t)(t0 + t)*32 + c] = a;
  }
}

// ---------------- final decoder: x_dyn = dec(zdyn) [1024 blk] + x_pred = dec(predz) [4 blk] ----
__global__ __launch_bounds__(256,4) void dec2_kernel(
    const float* __restrict__ za, const float* __restrict__ zb,
    const float* __restrict__ W1, const float* __restrict__ b1,
    const float* __restrict__ W2, const float* __restrict__ b2,
    float* __restrict__ outa, float* __restrict__ outb)
{
  __shared__ float s_z[8*64];
  __shared__ float s_h[8*64];
  const int tid = threadIdx.x;
  const float* src; float* dst; int t0;
  if (blockIdx.x < 1024) { src = za; dst = outa; t0 = blockIdx.x * 8; }
  else                   { src = zb; dst = outb; t0 = (blockIdx.x - 1024) * 8; }
  s_z[tid]       = src[(size_t)t0*64 + tid];
  s_z[tid + 256] = src[(size_t)t0*64 + tid + 256];
  __syncthreads();
  const int j = tid & 63, tg = tid >> 6;
  {
    float w[64];
    #pragma unroll
    for (int k = 0; k < 64; k++) w[k] = W1[k*64 + j];
    #pragma unroll
    for (int q = 0; q < 2; q++) {
      int t = tg*2 + q;
      float a = b1[j];
      #pragma unroll
      for (int k = 0; k < 64; k++) a = fmaf(s_z[t*64 + k], w[k], a);
      s_h[t*64 + j] = fmaxf(a, 0.f);
    }
  }
  __syncthreads();
  {
    const int c = tid & 31, t = tid >> 5;
    float a = b2[c];
    const float4* hh = (const float4*)&s_h[t*64];
    #pragma unroll
    for (int k4 = 0; k4 < 16; k4++) {
      float4 hv = hh[k4];
      a = fmaf(hv.x, W2[(k4*4+0)*32 + c], a);
      a = fmaf(hv.y, W2[(k4*4+1)*32 + c], a);
      a = fmaf(hv.z, W2[(k4*4+2)*32 + c], a);
      a = fmaf(hv.w, W2[(k4*4+3)*32 + c], a);
    }
    dst[(size_t)(t0 + t)*32 + c] = a;
  }
}

// ---------------- pre: 4 tokens/block (+3 halo), 2048 blocks ----------------
__global__ __launch_bounds__(256,8) void pre_kernel(
    const float* __restrict__ inbuf, const float* __restrict__ zsrc, const float* __restrict__ pzsrc, int shift,
    const float* __restrict__ Win, const float* __restrict__ Wconv, const float* __restrict__ bconv,
    const float* __restrict__ Wxproj, const float* __restrict__ Wdt, const float* __restrict__ bdt,
    float* __restrict__ xibuf, float* __restrict__ resgbuf,
    float2* __restrict__ ddbuf, float* __restrict__ Bbuf, float* __restrict__ Cbuf,
    float* __restrict__ xzout, int wstride)
{
  __shared__ float s_xi[4*128];
  __shared__ float s_dtr[4*4];
  const int tid = threadIdx.x;
  const int b  = blockIdx.x >> 8;
  const int t0 = (blockIdx.x & 255) * 4;

  const float* rowp[7];
  #pragma unroll
  for (int r = 0; r < 7; r++) {
    int tg = t0 - 3 + r;
    const float* rp = inbuf;
    if (tg >= 0) {
      if (zsrc) {
        int st = tg + shift;
        rp = (st < TLEN) ? zsrc + (size_t)(b*TLEN + st)*DM
                         : pzsrc + (size_t)(b*4 + (st - TLEN))*DM;
      } else {
        rp = inbuf + (size_t)(b*TLEN + tg)*DM;
      }
    }
    rowp[r] = rp;
  }

  float acc[7];
  #pragma unroll
  for (int r = 0; r < 7; r++) acc[r] = 0.f;

  if (t0 > 0) {
    #pragma unroll
    for (int k4 = 0; k4 < 16; k4++) {
      float w0 = Win[(k4*4+0)*256 + tid];
      float w1 = Win[(k4*4+1)*256 + tid];
      float w2 = Win[(k4*4+2)*256 + tid];
      float w3 = Win[(k4*4+3)*256 + tid];
      #pragma unroll
      for (int r = 0; r < 7; r++) {
        float4 xv = *(const float4*)(rowp[r] + k4*4);
        acc[r] = fmaf(xv.x, w0, acc[r]);
        acc[r] = fmaf(xv.y, w1, acc[r]);
        acc[r] = fmaf(xv.z, w2, acc[r]);
        acc[r] = fmaf(xv.w, w3, acc[r]);
      }
    }
  } else {
    #pragma unroll
    for (int k4 = 0; k4 < 16; k4++) {
      float w0 = Win[(k4*4+0)*256 + tid];
      float w1 = Win[(k4*4+1)*256 + tid];
      float w2 = Win[(k4*4+2)*256 + tid];
      float w3 = Win[(k4*4+3)*256 + tid];
      #pragma unroll
      for (int r = 3; r < 7; r++) {
        float4 xv = *(const float4*)(rowp[r] + k4*4);
        acc[r] = fmaf(xv.x, w0, acc[r]);
        acc[r] = fmaf(xv.y, w1, acc[r]);
        acc[r] = fmaf(xv.z, w2, acc[r]);
        acc[r] = fmaf(xv.w, w3, acc[r]);
      }
    }
  }

  if (tid < 128) {
    float4 wc = *(const float4*)&Wconv[tid*4];
    float bc = bconv[tid];
    #pragma unroll
    for (int tau = 0; tau < 4; tau++) {
      float v = bc;
      v = fmaf(acc[tau+0], wc.x, v);
      v = fmaf(acc[tau+1], wc.y, v);
      v = fmaf(acc[tau+2], wc.z, v);
      v = fmaf(acc[tau+3], wc.w, v);
      float xiv = siluf(v);
      s_xi[tau*128 + tid] = xiv;
      xibuf[((size_t)b*wstride + t0 + tau)*DI + tid] = xiv;
      if (xzout) xzout[((size_t)b*wstride + t0 + tau)*128 + tid] = acc[tau+3];
    }
  } else {
    int d = tid - 128;
    #pragma unroll
    for (int tau = 0; tau < 4; tau++)
      resgbuf[((size_t)b*wstride + t0 + tau)*DI + d] = siluf(acc[tau+3]);
  }
  __syncthreads();
  {
    const int wv = tid >> 6, c = tid & 63;
    float a0 = 0.f;
    const float4* x0 = (const float4*)&s_xi[wv*128];
    #pragma unroll 8
    for (int k4 = 0; k4 < 32; k4++) {
      float4 v0 = x0[k4];
      a0 = fmaf(v0.x, Wxproj[(k4*4+0)*68 + 4 + c],
           fmaf(v0.y, Wxproj[(k4*4+1)*68 + 4 + c],
           fmaf(v0.z, Wxproj[(k4*4+2)*68 + 4 + c],
           fmaf(v0.w, Wxproj[(k4*4+3)*68 + 4 + c], a0))));
    }
    size_t tb = (size_t)b*wstride + t0 + wv;
    if (c < 32) Bbuf[tb*DS + c] = a0;
    else        Cbuf[tb*DS + (c-32)] = a0;
  }
  if (tid < 16) {
    int tau = tid >> 2, cc = tid & 3;
    float a = 0.f;
    const float4* xx = (const float4*)&s_xi[tau*128];
    #pragma unroll 8
    for (int k4 = 0; k4 < 32; k4++) {
      float4 v = xx[k4];
      a = fmaf(v.x, Wxproj[(k4*4+0)*68 + cc], a);
      a = fmaf(v.y, Wxproj[(k4*4+1)*68 + cc], a);
      a = fmaf(v.z, Wxproj[(k4*4+2)*68 + cc], a);
      a = fmaf(v.w, Wxproj[(k4*4+3)*68 + cc], a);
    }
    s_dtr[tau*4 + cc] = a;
  }
  __syncthreads();
  #pragma unroll
  for (int u = 0; u < 2; u++) {
    int i = tid + u*256;
    int tau = i >> 7, d = i & 127;
    float a = bdt[d];
    #pragma unroll
    for (int r = 0; r < 4; r++) a = fmaf(s_dtr[tau*4 + r], Wdt[r*128 + d], a);
    float dtv = softplusf(a);
    ddbuf[((size_t)b*wstride + t0 + tau)*DI + d] = make_float2(dtv, dtv * s_xi[i]);
  }
}

// B/C chunk swizzle (r4): breaks the stride-68 8-way conflict down to <=2-way.
#define BSWZ(row3) (((row3)&3)<<1)

// ---------------- scan phase 1: per-chunk summary via group-anchored sums ----------------
__global__ __launch_bounds__(128,8) void scan1_kernel(
    const float2* __restrict__ ddbuf, const float* __restrict__ Bbuf,
    const float* __restrict__ Alog, float2* __restrict__ hc, int stride, int off)
{
  __shared__ float2 s_dd[4][CLEN];
  __shared__ float  s_Bt[32][68];
  const int tid = threadIdx.x;
  const int ch = tid >> 5, s = tid & 31;
  const int dg = blockIdx.x & 31;
  const int c  = (blockIdx.x >> 5) & 15;
  const int b  = blockIdx.x >> 9;
  const int d0 = dg * 4;
  const float A = -__expf(Alog[(d0 + ch)*DS + s]);
  const float2* ddg = ddbuf + ((size_t)b*stride + off + c*CLEN)*DI + d0;
  const float*  Bg  = Bbuf  + ((size_t)b*stride + off + c*CLEN)*DS;
  {
    int t = tid >> 1, half = tid & 1;
    float4 rdd = *(const float4*)((const float*)(ddg + (size_t)t*DI) + half*4);
    s_dd[2*half+0][t] = make_float2(rdd.x, rdd.y);
    s_dd[2*half+1][t] = make_float2(rdd.z, rdd.w);
    #pragma unroll
    for (int j = 0; j < 4; j++) {
      int q = tid + 128*j; int tt = q >> 3, k4 = q & 7;
      float4 rB = *(const float4*)(Bg + tt*DS + k4*4);
      int cp = (((tt>>2) ^ BSWZ(k4>>1)) << 2) + (tt & 3);
      s_Bt[k4*4+0][cp] = rB.x; s_Bt[k4*4+1][cp] = rB.y;
      s_Bt[k4*4+2][cp] = rB.z; s_Bt[k4*4+3][cp] = rB.w;
    }
  }
  __syncthreads();
  const float4* dd4 = (const float4*)&s_dd[ch][0];
  const float4* bt4 = (const float4*)&s_Bt[s][0];
  const int swr = BSWZ(s>>3);
  float h = 0.f, dectot = 1.f;
  #pragma unroll
  for (int j = 0; j < 8; j++) {
    float4 e0 = dd4[4*j+0], e1 = dd4[4*j+1], e2 = dd4[4*j+2], e3 = dd4[4*j+3];
    float4 bb0 = bt4[(2*j)^swr], bb1 = bt4[(2*j+1)^swr];
    float c1 = e0.x;
    float c2 = c1 + e0.z;
    float c3 = c2 + e1.x;
    float c4 = c3 + e1.z;
    float c5 = c4 + e2.x;
    float c6 = c5 + e2.z;
    float c7 = c6 + e3.x;
    float c8 = c7 + e3.z;
    float gl;
    gl  = e0.y*bb0.x*__expf(A*(c8 - c1));
    gl += e0.w*bb0.y*__expf(A*(c8 - c2));
    gl += e1.y*bb0.z*__expf(A*(c8 - c3));
    gl += e1.w*bb0.w*__expf(A*(c8 - c4));
    gl += e2.y*bb1.x*__expf(A*(c8 - c5));
    gl += e2.w*bb1.y*__expf(A*(c8 - c6));
    gl += e3.y*bb1.z*__expf(A*(c8 - c7));
    gl += e3.w*bb1.w;
    float gdec = __expf(A*c8);
    h = fmaf(gdec, h, gl);
    dectot *= gdec;
  }
  int o = ((b*NCHUNK + c)*DI + d0 + ch)*DS + s;
  hc[o] = make_float2(h, dectot);
}

// ---------------- scan phase 3: prefix-combine + rescan chunk, emit y ----------------
// conly >= 0: only chunk conly (grid 8*32); else all chunks (grid 8*16*32).
__global__ __launch_bounds__(128) void scan3_kernel(
    const float2* __restrict__ ddbuf, const float* __restrict__ Bbuf, const float* __restrict__ Cbuf,
    const float* __restrict__ Alog, const float2* __restrict__ hc, float* __restrict__ ysbuf,
    int conly, int stride, int off)
{
  __shared__ float2 s_dd[4][CLEN];
  __shared__ float  s_Bt[32][68];
  __shared__ float  s_Ct[32][68];
  __shared__ float  s_p[128][33];
  const int tid = threadIdx.x;
  const int ch = tid >> 5, s = tid & 31;
  const int dg = blockIdx.x & 31;
  const int c  = (conly >= 0) ? conly : ((blockIdx.x >> 5) & 15);
  const int b  = (conly >= 0) ? (blockIdx.x >> 5) : (blockIdx.x >> 9);
  const int d0 = dg * 4;
  const float A = -__expf(Alog[(d0 + ch)*DS + s]);
  const float2* ddg = ddbuf + ((size_t)b*stride + off + c*CLEN)*DI + d0;
  const float*  Bg  = Bbuf  + ((size_t)b*stride + off + c*CLEN)*DS;
  const float*  Cg  = Cbuf  + ((size_t)b*stride + off + c*CLEN)*DS;

  const int ob = (d0 + ch)*DS + s;
  float2 v[15];
  #pragma unroll
  for (int q = 0; q < 15; q++) v[q] = hc[(size_t)(b*NCHUNK + q)*4096 + ob];

  {
    int t = tid >> 1, half = tid & 1;
    float4 rdd = *(const float4*)((const float*)(ddg + (size_t)t*DI) + half*4);
    s_dd[2*half+0][t] = make_float2(rdd.x, rdd.y);
    s_dd[2*half+1][t] = make_float2(rdd.z, rdd.w);
    #pragma unroll
    for (int j = 0; j < 4; j++) {
      int q = tid + 128*j; int tt = q >> 3, k4 = q & 7;
      float4 rB = *(const float4*)(Bg + tt*DS + k4*4);
      float4 rC = *(const float4*)(Cg + tt*DS + k4*4);
      int cp = (((tt>>2) ^ BSWZ(k4>>1)) << 2) + (tt & 3);
      s_Bt[k4*4+0][cp] = rB.x; s_Bt[k4*4+1][cp] = rB.y;
      s_Bt[k4*4+2][cp] = rB.z; s_Bt[k4*4+3][cp] = rB.w;
      s_Ct[k4*4+0][cp] = rC.x; s_Ct[k4*4+1][cp] = rC.y;
      s_Ct[k4*4+2][cp] = rC.z; s_Ct[k4*4+3][cp] = rC.w;
    }
  }
  float h = 0.f;
  #pragma unroll
  for (int q = 0; q < 15; q++)
    if (q < c) h = fmaf(v[q].y, h, v[q].x);
  __syncthreads();

  const float4* dd4 = (const float4*)&s_dd[ch][0];
  const float4* bt4 = (const float4*)&s_Bt[s][0];
  const float4* ct4 = (const float4*)&s_Ct[s][0];
  const int swr = BSWZ(s>>3);
  float* pr = &s_p[tid][0];
  #pragma unroll
  for (int half = 0; half < 2; half++) {
    #pragma unroll
    for (int j = 0; j < 4; j++) {
      const int jj = half*4 + j;
      float4 e0 = dd4[4*jj+0], e1 = dd4[4*jj+1], e2 = dd4[4*jj+2], e3 = dd4[4*jj+3];
      float4 bb0 = bt4[(2*jj)^swr], bb1 = bt4[(2*jj+1)^swr];
      float4 cc0 = ct4[(2*jj)^swr], cc1 = ct4[(2*jj+1)^swr];
      h = fmaf(__expf(e0.x*A), h, e0.y*bb0.x); pr[8*j+0] = h*cc0.x;
      h = fmaf(__expf(e0.z*A), h, e0.w*bb0.y); pr[8*j+1] = h*cc0.y;
      h = fmaf(__expf(e1.x*A), h, e1.y*bb0.z); pr[8*j+2] = h*cc0.z;
      h = fmaf(__expf(e1.z*A), h, e1.w*bb0.w); pr[8*j+3] = h*cc0.w;
      h = fmaf(__expf(e2.x*A), h, e2.y*bb1.x); pr[8*j+4] = h*cc1.x;
      h = fmaf(__expf(e2.z*A), h, e2.w*bb1.y); pr[8*j+5] = h*cc1.y;
      h = fmaf(__expf(e3.x*A), h, e3.y*bb1.z); pr[8*j+6] = h*cc1.z;
      h = fmaf(__expf(e3.z*A), h, e3.w*bb1.w); pr[8*j+7] = h*cc1.w;
    }
    __syncthreads();
    {
      const int ch2 = tid & 3;
      const int tq  = tid >> 2;
      float a = 0.f;
      #pragma unroll
      for (int s2 = 0; s2 < 32; s2++) a += s_p[ch2*32 + s2][tq];
      ysbuf[(size_t)(b*TLEN + c*CLEN + half*32 + tq)*DI + d0 + ch2] = a;
    }
    __syncthreads();
  }
}

// ---------------- post: 4 tokens/block, 2048 blocks ----------------
__global__ __launch_bounds__(256,8) void post_kernel(
    const float* __restrict__ ysbuf, const float* __restrict__ xibuf, const float* __restrict__ resgbuf,
    const float* __restrict__ Dp, const float* __restrict__ Wout,
    const float* __restrict__ zsrc, const float* __restrict__ pzsrc, int shift,
    float* __restrict__ outbuf, float* __restrict__ zdyn, float* __restrict__ predz,
    const float* __restrict__ gamma, const float* __restrict__ beta, int mode,
    int rstride, int roff)
{
  __shared__ float s_y[4*128];
  const int tid = threadIdx.x;
  const int b  = blockIdx.x >> 8;
  const int t0 = (blockIdx.x & 255) * 4;
  #pragma unroll
  for (int u = 0; u < 2; u++) {
    int i = tid + u*256;
    size_t gy = (size_t)(b*TLEN + t0)*DI + i;
    size_t gx = ((size_t)b*rstride + roff + t0)*DI + i;
    s_y[i] = (ysbuf[gy] + xibuf[gx]*Dp[i & 127]) * resgbuf[gx];
  }
  __syncthreads();
  {
    const int tau = tid >> 6, c = tid & 63;
    float a = 0.f;
    const float4* yy = (const float4*)&s_y[tau*128];
    #pragma unroll 8
    for (int k4 = 0; k4 < 32; k4++) {
      float4 vv = yy[k4];
      a = fmaf(vv.x, Wout[(k4*4+0)*64 + c], a);
      a = fmaf(vv.y, Wout[(k4*4+1)*64 + c], a);
      a = fmaf(vv.z, Wout[(k4*4+2)*64 + c], a);
      a = fmaf(vv.w, Wout[(k4*4+3)*64 + c], a);
    }
    size_t g = (size_t)(b*TLEN + t0 + tau)*DM + c;
    float base;
    if (zsrc) {
      int st = t0 + tau + shift;
      base = (st < TLEN) ? zsrc[(size_t)(b*TLEN + st)*DM + c] : pzsrc[(size_t)(b*4 + (st - TLEN))*DM + c];
    } else {
      base = outbuf[g];
    }
    float val = base + a;
    if (mode == 0) {
      outbuf[g] = val;
    } else {
      float sum = val;
      #pragma unroll
      for (int m = 1; m < 64; m <<= 1) sum += __shfl_xor(sum, m);
      float mean = sum * (1.f/64.f);
      float dv = val - mean;
      float vs = dv*dv;
      #pragma unroll
      for (int m = 1; m < 64; m <<= 1) vs += __shfl_xor(vs, m);
      float oln = dv * rsqrtf(vs*(1.f/64.f) + 1e-5f) * gamma[c] + beta[c];
      zdyn[g] = oln;
      if (t0 + tau == TLEN-1) predz[(size_t)(b*4 + 0)*DM + c] = oln;
    }
  }
}

// ---------------- tiny_post: last token only, residual base = cur[1023], fused LN -> predz[slot] ----
__global__ __launch_bounds__(128) void tiny_post_kernel(
    const float* __restrict__ ysbuf, const float* __restrict__ xibuf, const float* __restrict__ resgbuf,
    const float* __restrict__ Dp, const float* __restrict__ Wout, const float* __restrict__ cur,
    float* __restrict__ predz, const float* __restrict__ gamma, const float* __restrict__ beta, int slot)
{
  __shared__ float s_y[128];
  const int tid = threadIdx.x;
  const int b = blockIdx.x;
  size_t g = (size_t)(b*TLEN + TLEN-1)*DI + tid;
  s_y[tid] = (ysbuf[g] + xibuf[g]*Dp[tid]) * resgbuf[g];
  __syncthreads();
  if (tid < 64) {
    float a = 0.f;
    #pragma unroll 4
    for (int k = 0; k < 128; k++) a = fmaf(s_y[k], Wout[k*64 + tid], a);
    float val = cur[(size_t)(b*TLEN + TLEN-1)*DM + tid] + a;
    float sum = val;
    #pragma unroll
    for (int m = 1; m < 64; m <<= 1) sum += __shfl_xor(sum, m);
    float mean = sum * (1.f/64.f);
    float dv = val - mean;
    float vs = dv*dv;
    #pragma unroll
    for (int m = 1; m < 64; m <<= 1) vs += __shfl_xor(vs, m);
    float oln = dv * rsqrtf(vs*(1.f/64.f) + 1e-5f) * gamma[tid] + beta[tid];
    predz[(size_t)(b*4 + slot)*DM + tid] = oln;
  }
}

// ---------------- patch: [tiny_post of pass p-1 from ysbuf] + recompute pre(i0) tokens
// {p, p+1, p+2, 1023+p}. 8 blocks, 256 threads.
__global__ __launch_bounds__(256) void patch_kernel(
    int p, int do_tp,
    const float* __restrict__ ysbuf, const float* __restrict__ cur,
    const float* __restrict__ xi1, const float* __restrict__ resg1,
    const float* __restrict__ Dp1, const float* __restrict__ Wout1,
    const float* __restrict__ gamma, const float* __restrict__ beta,
    float* __restrict__ predz,
    float* __restrict__ xz0,
    const float* __restrict__ Win0, const float* __restrict__ Wconv0, const float* __restrict__ bconv0,
    const float* __restrict__ Wxp0, const float* __restrict__ Wdt0, const float* __restrict__ bdt0,
    float* __restrict__ xi0, float* __restrict__ resg0,
    float2* __restrict__ dd0, float* __restrict__ Bb0, float* __restrict__ Cb0)
{
  __shared__ float s_pz[64];
  __shared__ float s_y[128];
  __shared__ float s_new[256];
  __shared__ float s_xi[4][128];
  __shared__ float s_dtr[4][4];
  const int tid = threadIdx.x;
  const int b = blockIdx.x;
  const int gn = 1023 + p;

  if (do_tp) {
    // tiny_post of pass p-1: predz[b][p-1] = LN(cur[1023] + y_last @ Wout1)
    if (tid < 128) {
      size_t g = (size_t)(b*TLEN + TLEN-1)*DI + tid;
      s_y[tid] = (ysbuf[g] + xi1[g]*Dp1[tid]) * resg1[g];
    }
    __syncthreads();
    if (tid < 64) {
      float a = 0.f;
      #pragma unroll 4
      for (int k = 0; k < 128; k++) a = fmaf(s_y[k], Wout1[k*64 + tid], a);
      float val = cur[(size_t)(b*TLEN + TLEN-1)*DM + tid] + a;
      float sum = val;
      #pragma unroll
      for (int m = 1; m < 64; m <<= 1) sum += __shfl_xor(sum, m);
      float mean = sum * (1.f/64.f);
      float dv = val - mean;
      float vs = dv*dv;
      #pragma unroll
      for (int m = 1; m < 64; m <<= 1) vs += __shfl_xor(vs, m);
      float oln = dv * rsqrtf(vs*(1.f/64.f) + 1e-5f) * gamma[tid] + beta[tid];
      predz[(size_t)(b*4 + p-1)*DM + tid] = oln;
      s_pz[tid] = oln;
    }
  } else {
    if (tid < 64) s_pz[tid] = predz[(size_t)(b*4 + p-1)*DM + tid];
  }
  __syncthreads();

  // phase 1: xz of the new token gn
  {
    float a = 0.f;
    #pragma unroll
    for (int k = 0; k < 64; k++) a = fmaf(s_pz[k], Win0[k*256 + tid], a);
    s_new[tid] = a;
  }
  __syncthreads();
  if (tid < 128) xz0[((size_t)b*GEXT + gn)*128 + tid] = s_new[tid];
  else           resg0[((size_t)b*GEXT + gn)*DI + (tid-128)] = siluf(s_new[tid]);

  // phase 2: conv + silu for 4 tokens x 128 ch
  #pragma unroll
  for (int jj = 0; jj < 2; jj++) {
    int job = tid + jj*256;
    int tok = job >> 7, d = job & 127;
    int g = (tok < 3) ? (p + tok) : gn;
    float a = bconv0[d];
    #pragma unroll
    for (int k = 0; k < 4; k++) {
      int row = g - 3 + k;
      float xv;
      if (tok < 3) xv = (row >= p) ? xz0[((size_t)b*GEXT + row)*128 + d] : 0.f;
      else         xv = (k < 3) ? xz0[((size_t)b*GEXT + row)*128 + d] : s_new[d];
      a = fmaf(xv, Wconv0[d*4 + k], a);
    }
    float xiv = siluf(a);
    s_xi[tok][d] = xiv;
    xi0[((size_t)b*GEXT + g)*DI + d] = xiv;
  }
  __syncthreads();

  // phase 3: xproj: 4 tokens x 68 cols = 272 jobs
  #pragma unroll
  for (int jj = 0; jj < 2; jj++) {
    int job = tid + jj*256;
    if (job < 272) {
      int tok = job / 68, c = job % 68;
      int g = (tok < 3) ? (p + tok) : gn;
      float a = 0.f;
      #pragma unroll 4
      for (int k = 0; k < 128; k++) a = fmaf(s_xi[tok][k], Wxp0[k*68 + c], a);
      if (c < 4)        s_dtr[tok][c] = a;
      else if (c < 36)  Bb0[((size_t)b*GEXT + g)*DS + (c - 4)]  = a;
      else              Cb0[((size_t)b*GEXT + g)*DS + (c - 36)] = a;
    }
  }
  __syncthreads();

  // phase 4: dt + dd
  #pragma unroll
  for (int jj = 0; jj < 2; jj++) {
    int job = tid + jj*256;
    int tok = job >> 7, d = job & 127;
    int g = (tok < 3) ? (p + tok) : gn;
    float a = bdt0[d];
    #pragma unroll
    for (int r = 0; r < 4; r++) a = fmaf(s_dtr[tok][r], Wdt0[r*128 + d], a);
    float dtv = softplusf(a);
    dd0[((size_t)b*GEXT + g)*DI + d] = make_float2(dtv, dtv * s_xi[tok][d]);
  }
}

extern "C" void kernel_launch(void* const* d_in, const int* in_sizes, int n_in,
                              void* d_out, int out_size, void* d_ws, size_t ws_size,
                              hipStream_t stream)
{
  (void)in_sizes; (void)n_in; (void)out_size; (void)ws_size;
  const float* x     = (const float*)d_in[0];
  const float* We1   = (const float*)d_in[1];
  const float* be1   = (const float*)d_in[2];
  const float* We2   = (const float*)d_in[3];
  const float* be2   = (const float*)d_in[4];
  const float* Wd1   = (const float*)d_in[5];
  const float* bd1   = (const float*)d_in[6];
  const float* Wd2   = (const float*)d_in[7];
  const float* bd2   = (const float*)d_in[8];
  const float* Win   = (const float*)d_in[9];
  const float* Wconv = (const float*)d_in[10];
  const float* bconv = (const float*)d_in[11];
  const float* Wxp   = (const float*)d_in[12];
  const float* Wdt   = (const float*)d_in[13];
  const float* bdt   = (const float*)d_in[14];
  const float* Alog  = (const float*)d_in[15];
  const float* Dp    = (const float*)d_in[16];
  const float* Wout  = (const float*)d_in[17];
  const float* gamma = (const float*)d_in[18];
  const float* beta  = (const float*)d_in[19];

  float* o      = (float*)d_out;
  float* x_rec  = o;                 // 8*1024*32
  float* x_dyn  = o + 262144;        // 8*1024*32
  float* x_pred = o + 524288;        // 8*4*32
  float* z      = o + 525312;        // 8*1024*64
  float* zdyn   = o + 1049600;       // 8*1024*64

  float* w     = (float*)d_ws;
  float* cur   = w;                            // 524288
  float* xi1   = cur  + 524288;                // 1048576
  float* resg1 = xi1  + 1048576;               // 1048576
  float2* dd1  = (float2*)(resg1 + 1048576);   // 2097152 floats
  float* Bb1   = resg1 + 1048576 + 2097152;    // 262144
  float* Cb1   = Bb1  + 262144;                // 262144
  float* ys    = Cb1  + 262144;                // 1048576
  float2* hc   = (float2*)(ys + 1048576);      // 1048576 floats
  float* predz = ys + 1048576 + 1048576;       // 2048
  float* xi0   = predz + 2048;                 // 1052672 (8*1028*128)
  float* resg0 = xi0  + 1052672;               // 1052672
  float2* dd0  = (float2*)(resg0 + 1052672);   // 2105344 floats
  float* Bb0   = resg0 + 1052672 + 2105344;    // 263168 (8*1028*32)
  float* Cb0   = Bb0  + 263168;                // 263168
  float* xz0   = Cb0  + 263168;                // 1052672

  const float* Win0 = Win,   *Win1 = Win + 64*256;
  const float* Wcv0 = Wconv, *Wcv1 = Wconv + 128*4;
  const float* bcv0 = bconv, *bcv1 = bconv + 128;
  const float* Wxp0 = Wxp,   *Wxp1 = Wxp + 128*68;
  const float* Wdt0 = Wdt,   *Wdt1 = Wdt + 4*128;
  const float* bdt0 = bdt,   *bdt1 = bdt + 128;
  const float* Al0  = Alog,  *Al1  = Alog + 128*32;
  const float* Dp0  = Dp,    *Dp1  = Dp + 128;
  const float* Wo0  = Wout,  *Wo1  = Wout + 128*64;

  // encoder + reconstruction decoder (fused)
  enc_xrec_kernel<<<dim3(1024), dim3(256), 0, stream>>>(x, We1, be1, We2, be2, Wd1, bd1, Wd2, bd2, z, x_rec);

  // pre(i=0) ONCE over global z tokens, storing xz xi-half
  pre_kernel<<<dim3(2048), dim3(256), 0, stream>>>(cur, z, predz, 0,
                                                   Win0, Wcv0, bcv0, Wxp0, Wdt0, bdt0,
                                                   xi0, resg0, dd0, Bb0, Cb0, xz0, GEXT);

  for (int p = 0; p < 4; p++) {
    if (p >= 1) {
      // patch: tiny_post of pass p-1 (for p>=2, from ys of prev pass's scan3-small) + pre(i0) patch
      patch_kernel<<<dim3(8), dim3(256), 0, stream>>>(p, (p >= 2) ? 1 : 0,
          ys, cur, xi1, resg1, Dp1, Wo1, gamma, beta, predz,
          xz0, Win0, Wcv0, bcv0, Wxp0, Wdt0, bdt0,
          xi0, resg0, dd0, Bb0, Cb0);
    }
    // ---- block i=0 (shared pre buffers, window at offset p) ----
    scan1_kernel<<<dim3(4096), dim3(128), 0, stream>>>(dd0, Bb0, Al0, hc, GEXT, p);
    scan3_kernel<<<dim3(4096), dim3(128), 0, stream>>>(dd0, Bb0, Cb0, Al0, hc, ys, -1, GEXT, p);
    post_kernel<<<dim3(2048), dim3(256), 0, stream>>>(ys, xi0, resg0, Dp0, Wo0,
                                                      z, predz, p, cur,
                                                      (float*)nullptr, (float*)nullptr,
                                                      (const float*)nullptr, (const float*)nullptr, 0,
                                                      GEXT, p);
    // ---- block i=1 (pass-local) ----
    pre_kernel<<<dim3(2048), dim3(256), 0, stream>>>(cur, (const float*)nullptr, (const float*)nullptr, 0,
                                                     Win1, Wcv1, bcv1, Wxp1, Wdt1, bdt1,
                                                     xi1, resg1, dd1, Bb1, Cb1, (float*)nullptr, TLEN);
    scan1_kernel<<<dim3(4096), dim3(128), 0, stream>>>(dd1, Bb1, Al1, hc, TLEN, 0);
    if (p == 0) {
      scan3_kernel<<<dim3(4096), dim3(128), 0, stream>>>(dd1, Bb1, Cb1, Al1, hc, ys, -1, TLEN, 0);
      post_kernel<<<dim3(2048), dim3(256), 0, stream>>>(ys, xi1, resg1, Dp1, Wo1,
                                                        (const float*)nullptr, (const float*)nullptr, 0, cur,
                                                        zdyn, predz, gamma, beta, 1, TLEN, 0);
    } else {
      // last chunk only -> ys tokens 960..1023 (token 1023 consumed by next patch / final tiny_post)
      scan3_kernel<<<dim3(256), dim3(128), 0, stream>>>(dd1, Bb1, Cb1, Al1, hc, ys, 15, TLEN, 0);
    }
  }

  // finish: predz[3] from pass-3 block-1 ys
  tiny_post_kernel<<<dim3(8), dim3(128), 0, stream>>>(ys, xi1, resg1, Dp1, Wo1, cur,
                                                      predz, gamma, beta, 3);

  // x_dyn = dec(zdyn) + x_pred = dec(predz)
  dec2_kernel<<<dim3(1028), dim3(256), 0, stream>>>(zdyn, predz, Wd1, bd1, Wd2, bd2, x_dyn, x_pred);
}

// Round 10
// 492.755 us; speedup vs baseline: 1.1806x; 1.1082x over previous
//
#include <hip/hip_runtime.h>

#define BSZ 8
#define TLEN 1024
#define DM 64
#define DI 128
#define DS 32
#define NTOK (BSZ*TLEN)
#define NCHUNK 16
#define CLEN 64
#define GEXT 1028   // 1024 z-tokens + up to 4 predz tokens (global token axis for block-0 buffers)

__device__ __forceinline__ float siluf(float x) { return x / (1.f + expf(-x)); }
__device__ __forceinline__ float softplusf(float x) { return (x > 20.f) ? x : log1pf(expf(x)); }

// ---------------- fused encoder + reconstruction decoder: 16 tokens/block, 512 blocks ----------------
__global__ __launch_bounds__(256) void enc_xrec_kernel(
    const float* __restrict__ x,
    const float* __restrict__ We1, const float* __restrict__ be1,
    const float* __restrict__ We2, const float* __restrict__ be2,
    const float* __restrict__ Wd1, const float* __restrict__ bd1,
    const float* __restrict__ Wd2, const float* __restrict__ bd2,
    float* __restrict__ z, float* __restrict__ x_rec)
{
  __shared__ float s_x[16*32];
  __shared__ float s_h1[16*64];
  __shared__ float s_z[16*64];
  __shared__ float s_h2[16*64];
  const int tid = threadIdx.x;
  const int t0 = blockIdx.x * 16;
  s_x[tid]       = x[(size_t)t0*32 + tid];
  s_x[tid + 256] = x[(size_t)t0*32 + tid + 256];
  __syncthreads();
  const int j = tid & 63, tg = tid >> 6;
  { // enc stage 1
    float w[32];
    #pragma unroll
    for (int k = 0; k < 32; k++) w[k] = We1[k*64 + j];
    #pragma unroll
    for (int q = 0; q < 4; q++) {
      int t = tg*4 + q;
      float a = be1[j];
      #pragma unroll
      for (int k = 0; k < 32; k++) a = fmaf(s_x[t*32 + k], w[k], a);
      s_h1[t*64 + j] = fmaxf(a, 0.f);
    }
  }
  __syncthreads();
  { // enc stage 2 -> z
    float w[64];
    #pragma unroll
    for (int k = 0; k < 64; k++) w[k] = We2[k*64 + j];
    #pragma unroll
    for (int q = 0; q < 4; q++) {
      int t = tg*4 + q;
      float a = be2[j];
      #pragma unroll
      for (int k = 0; k < 64; k++) a = fmaf(s_h1[t*64 + k], w[k], a);
      s_z[t*64 + j] = a;
      z[(size_t)(t0 + t)*64 + j] = a;
    }
  }
  __syncthreads();
  { // dec stage 1
    float w[64];
    #pragma unroll
    for (int k = 0; k < 64; k++) w[k] = Wd1[k*64 + j];
    #pragma unroll
    for (int q = 0; q < 4; q++) {
      int t = tg*4 + q;
      float a = bd1[j];
      #pragma unroll
      for (int k = 0; k < 64; k++) a = fmaf(s_z[t*64 + k], w[k], a);
      s_h2[t*64 + j] = fmaxf(a, 0.f);
    }
  }
  __syncthreads();
  { // dec stage 2 -> x_rec
    const int c = tid & 31, tg2 = tid >> 5;
    float w[64];
    #pragma unroll
    for (int k = 0; k < 64; k++) w[k] = Wd2[k*32 + c];
    #pragma unroll
    for (int q = 0; q < 2; q++) {
      int t = tg2*2 + q;
      float a = bd2[c];
      #pragma unroll
      for (int k = 0; k < 64; k++) a = fmaf(s_h2[t*64 + k], w[k], a);
      x_rec[(size_t)(t0 + t)*32 + c] = a;
    }
  }
}

// ---------------- final decoder: x_dyn = dec(zdyn) [512 blk] + x_pred = dec(predz) [2 blk] ----
__global__ __launch_bounds__(256) void dec2_kernel(
    const float* __restrict__ za, const float* __restrict__ zb,
    const float* __restrict__ W1, const float* __restrict__ b1,
    const float* __restrict__ W2, const float* __restrict__ b2,
    float* __restrict__ outa, float* __restrict__ outb)
{
  __shared__ float s_z[16*64];
  __shared__ float s_h[16*64];
  const int tid = threadIdx.x;
  const float* src; float* dst; int t0;
  if (blockIdx.x < 512) { src = za; dst = outa; t0 = blockIdx.x * 16; }
  else                  { src = zb; dst = outb; t0 = (blockIdx.x - 512) * 16; }
  #pragma unroll
  for (int u = 0; u < 4; u++) s_z[tid + u*256] = src[(size_t)t0*64 + tid + u*256];
  __syncthreads();
  const int j = tid & 63, tg = tid >> 6;
  {
    float w[64];
    #pragma unroll
    for (int k = 0; k < 64; k++) w[k] = W1[k*64 + j];
    #pragma unroll
    for (int q = 0; q < 4; q++) {
      int t = tg*4 + q;
      float a = b1[j];
      #pragma unroll
      for (int k = 0; k < 64; k++) a = fmaf(s_z[t*64 + k], w[k], a);
      s_h[t*64 + j] = fmaxf(a, 0.f);
    }
  }
  __syncthreads();
  {
    const int c = tid & 31, tg2 = tid >> 5;
    float w[64];
    #pragma unroll
    for (int k = 0; k < 64; k++) w[k] = W2[k*32 + c];
    #pragma unroll
    for (int q = 0; q < 2; q++) {
      int t = tg2*2 + q;
      float a = b2[c];
      #pragma unroll
      for (int k = 0; k < 64; k++) a = fmaf(s_h[t*64 + k], w[k], a);
      dst[(size_t)(t0 + t)*32 + c] = a;
    }
  }
}

// ---------------- pre: 8 tokens/block (+3 halo), 1024 blocks ----------------
__global__ __launch_bounds__(256,4) void pre_kernel(
    const float* __restrict__ inbuf, const float* __restrict__ zsrc, const float* __restrict__ pzsrc, int shift,
    const float* __restrict__ Win, const float* __restrict__ Wconv, const float* __restrict__ bconv,
    const float* __restrict__ Wxproj, const float* __restrict__ Wdt, const float* __restrict__ bdt,
    float* __restrict__ xibuf, float* __restrict__ resgbuf,
    float2* __restrict__ ddbuf, float* __restrict__ Bbuf, float* __restrict__ Cbuf,
    float* __restrict__ xzout, int wstride)
{
  __shared__ float s_xi[8*128];
  __shared__ float s_dtr[8*4];
  const int tid = threadIdx.x;
  const int b  = blockIdx.x >> 7;
  const int t0 = (blockIdx.x & 127) * 8;

  const float* rowp[11];
  #pragma unroll
  for (int r = 0; r < 11; r++) {
    int tg = t0 - 3 + r;
    const float* rp = inbuf;
    if (tg >= 0) {
      if (zsrc) {
        int st = tg + shift;
        rp = (st < TLEN) ? zsrc + (size_t)(b*TLEN + st)*DM
                         : pzsrc + (size_t)(b*4 + (st - TLEN))*DM;
      } else {
        rp = inbuf + (size_t)(b*TLEN + tg)*DM;
      }
    }
    rowp[r] = rp;
  }

  float acc[11];
  #pragma unroll
  for (int r = 0; r < 11; r++) acc[r] = 0.f;

  if (t0 > 0) {
    #pragma unroll
    for (int k4 = 0; k4 < 16; k4++) {
      float w0 = Win[(k4*4+0)*256 + tid];
      float w1 = Win[(k4*4+1)*256 + tid];
      float w2 = Win[(k4*4+2)*256 + tid];
      float w3 = Win[(k4*4+3)*256 + tid];
      #pragma unroll
      for (int r = 0; r < 11; r++) {
        float4 xv = *(const float4*)(rowp[r] + k4*4);
        acc[r] = fmaf(xv.x, w0, acc[r]);
        acc[r] = fmaf(xv.y, w1, acc[r]);
        acc[r] = fmaf(xv.z, w2, acc[r]);
        acc[r] = fmaf(xv.w, w3, acc[r]);
      }
    }
  } else {
    #pragma unroll
    for (int k4 = 0; k4 < 16; k4++) {
      float w0 = Win[(k4*4+0)*256 + tid];
      float w1 = Win[(k4*4+1)*256 + tid];
      float w2 = Win[(k4*4+2)*256 + tid];
      float w3 = Win[(k4*4+3)*256 + tid];
      #pragma unroll
      for (int r = 3; r < 11; r++) {
        float4 xv = *(const float4*)(rowp[r] + k4*4);
        acc[r] = fmaf(xv.x, w0, acc[r]);
        acc[r] = fmaf(xv.y, w1, acc[r]);
        acc[r] = fmaf(xv.z, w2, acc[r]);
        acc[r] = fmaf(xv.w, w3, acc[r]);
      }
    }
  }

  if (tid < 128) {
    float4 wc = *(const float4*)&Wconv[tid*4];
    float bc = bconv[tid];
    #pragma unroll
    for (int tau = 0; tau < 8; tau++) {
      float v = bc;
      v = fmaf(acc[tau+0], wc.x, v);
      v = fmaf(acc[tau+1], wc.y, v);
      v = fmaf(acc[tau+2], wc.z, v);
      v = fmaf(acc[tau+3], wc.w, v);
      float xiv = siluf(v);
      s_xi[tau*128 + tid] = xiv;
      xibuf[((size_t)b*wstride + t0 + tau)*DI + tid] = xiv;
      if (xzout) xzout[((size_t)b*wstride + t0 + tau)*128 + tid] = acc[tau+3];
    }
  } else {
    int d = tid - 128;
    #pragma unroll
    for (int tau = 0; tau < 8; tau++)
      resgbuf[((size_t)b*wstride + t0 + tau)*DI + d] = siluf(acc[tau+3]);
  }
  __syncthreads();
  {
    const int wv = tid >> 6, c = tid & 63;
    float a0 = 0.f, a1 = 0.f;
    const float4* x0 = (const float4*)&s_xi[(wv*2+0)*128];
    const float4* x1 = (const float4*)&s_xi[(wv*2+1)*128];
    #pragma unroll 4
    for (int k4 = 0; k4 < 32; k4++) {
      float wq0 = Wxproj[(k4*4+0)*68 + 4 + c];
      float wq1 = Wxproj[(k4*4+1)*68 + 4 + c];
      float wq2 = Wxproj[(k4*4+2)*68 + 4 + c];
      float wq3 = Wxproj[(k4*4+3)*68 + 4 + c];
      float4 v0 = x0[k4], v1 = x1[k4];
      a0 = fmaf(v0.x,wq0, fmaf(v0.y,wq1, fmaf(v0.z,wq2, fmaf(v0.w,wq3, a0))));
      a1 = fmaf(v1.x,wq0, fmaf(v1.y,wq1, fmaf(v1.z,wq2, fmaf(v1.w,wq3, a1))));
    }
    size_t tb = (size_t)b*wstride + t0 + wv*2;
    if (c < 32) {
      Bbuf[(tb+0)*DS + c] = a0; Bbuf[(tb+1)*DS + c] = a1;
    } else {
      int cc = c - 32;
      Cbuf[(tb+0)*DS + cc] = a0; Cbuf[(tb+1)*DS + cc] = a1;
    }
  }
  if (tid < 32) {
    int tau = tid >> 2, cc = tid & 3;
    float a = 0.f;
    const float4* xx = (const float4*)&s_xi[tau*128];
    #pragma unroll 4
    for (int k4 = 0; k4 < 32; k4++) {
      float4 v = xx[k4];
      a = fmaf(v.x, Wxproj[(k4*4+0)*68 + cc], a);
      a = fmaf(v.y, Wxproj[(k4*4+1)*68 + cc], a);
      a = fmaf(v.z, Wxproj[(k4*4+2)*68 + cc], a);
      a = fmaf(v.w, Wxproj[(k4*4+3)*68 + cc], a);
    }
    s_dtr[tau*4 + cc] = a;
  }
  __syncthreads();
  #pragma unroll
  for (int u = 0; u < 4; u++) {
    int i = tid + u*256;
    int tau = i >> 7, d = i & 127;
    float a = bdt[d];
    #pragma unroll
    for (int r = 0; r < 4; r++) a = fmaf(s_dtr[tau*4 + r], Wdt[r*128 + d], a);
    float dtv = softplusf(a);
    ddbuf[((size_t)b*wstride + t0 + tau)*DI + d] = make_float2(dtv, dtv * s_xi[i]);
  }
}

// B/C chunk swizzle (r4): breaks the stride-68 8-way conflict down to <=2-way.
#define BSWZ(row3) (((row3)&3)<<1)

// XCD work swizzle: the 32 dg-blocks of one (b,chunk) share dd/B/C cachelines
// (a 128B line spans 16 channels; each block uses 4). Map work so consecutive
// work-ids have the same blockIdx%8 -> co-XCD -> each line fetched once per XCD.
__device__ __forceinline__ int xcd_wid_4096() {
  return (blockIdx.x >> 3) | ((blockIdx.x & 7) << 9);
}

// ---------------- scan phase 1: per-chunk local scan from h=0; emits (h_end, decay) ----------------
__global__ __launch_bounds__(128) void scan1_kernel(
    const float2* __restrict__ ddbuf, const float* __restrict__ Bbuf,
    const float* __restrict__ Alog, float2* __restrict__ hc, int stride, int off)
{
  __shared__ float2 s_dd[4][CLEN];
  __shared__ float  s_Bt[32][68];
  const int tid = threadIdx.x;
  const int ch = tid >> 5, s = tid & 31;
  const int wid = xcd_wid_4096();
  const int dg = wid & 31;
  const int c  = (wid >> 5) & 15;
  const int b  = wid >> 9;
  const int d0 = dg * 4;
  const float A = -__expf(Alog[(d0 + ch)*DS + s]);
  const float2* ddg = ddbuf + ((size_t)b*stride + off + c*CLEN)*DI + d0;
  const float*  Bg  = Bbuf  + ((size_t)b*stride + off + c*CLEN)*DS;
  {
    int t = tid >> 1, half = tid & 1;
    float4 rdd = *(const float4*)((const float*)(ddg + (size_t)t*DI) + half*4);
    s_dd[2*half+0][t] = make_float2(rdd.x, rdd.y);
    s_dd[2*half+1][t] = make_float2(rdd.z, rdd.w);
    #pragma unroll
    for (int j = 0; j < 4; j++) {
      int q = tid + 128*j; int tt = q >> 3, k4 = q & 7;
      float4 rB = *(const float4*)(Bg + tt*DS + k4*4);
      int cp = (((tt>>2) ^ BSWZ(k4>>1)) << 2) + (tt & 3);
      s_Bt[k4*4+0][cp] = rB.x; s_Bt[k4*4+1][cp] = rB.y;
      s_Bt[k4*4+2][cp] = rB.z; s_Bt[k4*4+3][cp] = rB.w;
    }
  }
  __syncthreads();
  float h = 0.f, dts = 0.f;
  const float4* dd4 = (const float4*)&s_dd[ch][0];
  const float4* bt4 = (const float4*)&s_Bt[s][0];
  const int swr = BSWZ(s>>3);
  #pragma unroll
  for (int j = 0; j < 8; j++) {
    float4 e0 = dd4[4*j+0], e1 = dd4[4*j+1], e2 = dd4[4*j+2], e3 = dd4[4*j+3];
    float4 bb0 = bt4[(2*j)^swr], bb1 = bt4[(2*j+1)^swr];
    h = fmaf(__expf(e0.x*A), h, e0.y*bb0.x);
    h = fmaf(__expf(e0.z*A), h, e0.w*bb0.y);
    h = fmaf(__expf(e1.x*A), h, e1.y*bb0.z);
    h = fmaf(__expf(e1.z*A), h, e1.w*bb0.w);
    h = fmaf(__expf(e2.x*A), h, e2.y*bb1.x);
    h = fmaf(__expf(e2.z*A), h, e2.w*bb1.y);
    h = fmaf(__expf(e3.x*A), h, e3.y*bb1.z);
    h = fmaf(__expf(e3.z*A), h, e3.w*bb1.w);
    dts += (e0.x + e0.z) + (e1.x + e1.z) + (e2.x + e2.z) + (e3.x + e3.z);
  }
  int o = ((b*NCHUNK + c)*DI + d0 + ch)*DS + s;
  hc[o] = make_float2(h, __expf(A*dts));
}

// ---------------- scan phase 3: prefix-combine + rescan chunk, emit y ----------------
// conly >= 0: only chunk conly (grid 8*32); else all chunks (grid 8*16*32).
__global__ __launch_bounds__(128) void scan3_kernel(
    const float2* __restrict__ ddbuf, const float* __restrict__ Bbuf, const float* __restrict__ Cbuf,
    const float* __restrict__ Alog, const float2* __restrict__ hc, float* __restrict__ ysbuf,
    int conly, int stride, int off)
{
  __shared__ float2 s_dd[4][CLEN];
  __shared__ float  s_Bt[32][68];
  __shared__ float  s_Ct[32][68];
  __shared__ float  s_p[128][33];
  const int tid = threadIdx.x;
  const int ch = tid >> 5, s = tid & 31;
  int dg, c, b;
  if (conly >= 0) {
    int wid = (blockIdx.x >> 3) | ((blockIdx.x & 7) << 5);
    dg = wid & 31; c = conly; b = wid >> 5;
  } else {
    int wid = xcd_wid_4096();
    dg = wid & 31; c = (wid >> 5) & 15; b = wid >> 9;
  }
  const int d0 = dg * 4;
  const float A = -__expf(Alog[(d0 + ch)*DS + s]);
  const float2* ddg = ddbuf + ((size_t)b*stride + off + c*CLEN)*DI + d0;
  const float*  Bg  = Bbuf  + ((size_t)b*stride + off + c*CLEN)*DS;
  const float*  Cg  = Cbuf  + ((size_t)b*stride + off + c*CLEN)*DS;

  const int ob = (d0 + ch)*DS + s;
  float2 v[15];
  #pragma unroll
  for (int q = 0; q < 15; q++) v[q] = hc[(size_t)(b*NCHUNK + q)*4096 + ob];

  {
    int t = tid >> 1, half = tid & 1;
    float4 rdd = *(const float4*)((const float*)(ddg + (size_t)t*DI) + half*4);
    s_dd[2*half+0][t] = make_float2(rdd.x, rdd.y);
    s_dd[2*half+1][t] = make_float2(rdd.z, rdd.w);
    #pragma unroll
    for (int j = 0; j < 4; j++) {
      int q = tid + 128*j; int tt = q >> 3, k4 = q & 7;
      float4 rB = *(const float4*)(Bg + tt*DS + k4*4);
      float4 rC = *(const float4*)(Cg + tt*DS + k4*4);
      int cp = (((tt>>2) ^ BSWZ(k4>>1)) << 2) + (tt & 3);
      s_Bt[k4*4+0][cp] = rB.x; s_Bt[k4*4+1][cp] = rB.y;
      s_Bt[k4*4+2][cp] = rB.z; s_Bt[k4*4+3][cp] = rB.w;
      s_Ct[k4*4+0][cp] = rC.x; s_Ct[k4*4+1][cp] = rC.y;
      s_Ct[k4*4+2][cp] = rC.z; s_Ct[k4*4+3][cp] = rC.w;
    }
  }
  float h = 0.f;
  #pragma unroll
  for (int q = 0; q < 15; q++)
    if (q < c) h = fmaf(v[q].y, h, v[q].x);
  __syncthreads();

  const float4* dd4 = (const float4*)&s_dd[ch][0];
  const float4* bt4 = (const float4*)&s_Bt[s][0];
  const float4* ct4 = (const float4*)&s_Ct[s][0];
  const int swr = BSWZ(s>>3);
  float* pr = &s_p[tid][0];
  #pragma unroll
  for (int half = 0; half < 2; half++) {
    #pragma unroll
    for (int j = 0; j < 4; j++) {
      const int jj = half*4 + j;
      float4 e0 = dd4[4*jj+0], e1 = dd4[4*jj+1], e2 = dd4[4*jj+2], e3 = dd4[4*jj+3];
      float4 bb0 = bt4[(2*jj)^swr], bb1 = bt4[(2*jj+1)^swr];
      float4 cc0 = ct4[(2*jj)^swr], cc1 = ct4[(2*jj+1)^swr];
      h = fmaf(__expf(e0.x*A), h, e0.y*bb0.x); pr[8*j+0] = h*cc0.x;
      h = fmaf(__expf(e0.z*A), h, e0.w*bb0.y); pr[8*j+1] = h*cc0.y;
      h = fmaf(__expf(e1.x*A), h, e1.y*bb0.z); pr[8*j+2] = h*cc0.z;
      h = fmaf(__expf(e1.z*A), h, e1.w*bb0.w); pr[8*j+3] = h*cc0.w;
      h = fmaf(__expf(e2.x*A), h, e2.y*bb1.x); pr[8*j+4] = h*cc1.x;
      h = fmaf(__expf(e2.z*A), h, e2.w*bb1.y); pr[8*j+5] = h*cc1.y;
      h = fmaf(__expf(e3.x*A), h, e3.y*bb1.z); pr[8*j+6] = h*cc1.z;
      h = fmaf(__expf(e3.z*A), h, e3.w*bb1.w); pr[8*j+7] = h*cc1.w;
    }
    __syncthreads();
    {
      const int ch2 = tid & 3;
      const int tq  = tid >> 2;
      float a = 0.f;
      #pragma unroll
      for (int s2 = 0; s2 < 32; s2++) a += s_p[ch2*32 + s2][tq];
      ysbuf[(size_t)(b*TLEN + c*CLEN + half*32 + tq)*DI + d0 + ch2] = a;
    }
    __syncthreads();
  }
}

// ---------------- post: 8 tokens/block, 1024 blocks ----------------
__global__ __launch_bounds__(256,4) void post_kernel(
    const float* __restrict__ ysbuf, const float* __restrict__ xibuf, const float* __restrict__ resgbuf,
    const float* __restrict__ Dp, const float* __restrict__ Wout,
    const float* __restrict__ zsrc, const float* __restrict__ pzsrc, int shift,
    float* __restrict__ outbuf, float* __restrict__ zdyn, float* __restrict__ predz,
    const float* __restrict__ gamma, const float* __restrict__ beta, int mode,
    int rstride, int roff)
{
  __shared__ float s_y[8*128];
  const int tid = threadIdx.x;
  const int b  = blockIdx.x >> 7;
  const int t0 = (blockIdx.x & 127) * 8;
  #pragma unroll
  for (int u = 0; u < 4; u++) {
    int i = tid + u*256;
    size_t gy = (size_t)(b*TLEN + t0)*DI + i;
    size_t gx = ((size_t)b*rstride + roff + t0)*DI + i;
    s_y[i] = (ysbuf[gy] + xibuf[gx]*Dp[i & 127]) * resgbuf[gx];
  }
  __syncthreads();
  #pragma unroll
  for (int u = 0; u < 2; u++) {
    int i = tid + u*256;
    int tau = i >> 6, c = i & 63;
    float a = 0.f;
    const float4* yy = (const float4*)&s_y[tau*128];
    #pragma unroll 4
    for (int k4 = 0; k4 < 32; k4++) {
      float4 vv = yy[k4];
      a = fmaf(vv.x, Wout[(k4*4+0)*64 + c], a);
      a = fmaf(vv.y, Wout[(k4*4+1)*64 + c], a);
      a = fmaf(vv.z, Wout[(k4*4+2)*64 + c], a);
      a = fmaf(vv.w, Wout[(k4*4+3)*64 + c], a);
    }
    size_t g = (size_t)(b*TLEN + t0 + tau)*DM + c;
    float base;
    if (zsrc) {
      int st = t0 + tau + shift;
      base = (st < TLEN) ? zsrc[(size_t)(b*TLEN + st)*DM + c] : pzsrc[(size_t)(b*4 + (st - TLEN))*DM + c];
    } else {
      base = outbuf[g];
    }
    float val = base + a;
    if (mode == 0) {
      outbuf[g] = val;
    } else {
      float sum = val;
      #pragma unroll
      for (int m = 1; m < 64; m <<= 1) sum += __shfl_xor(sum, m);
      float mean = sum * (1.f/64.f);
      float dv = val - mean;
      float vs = dv*dv;
      #pragma unroll
      for (int m = 1; m < 64; m <<= 1) vs += __shfl_xor(vs, m);
      float oln = dv * rsqrtf(vs*(1.f/64.f) + 1e-5f) * gamma[c] + beta[c];
      zdyn[g] = oln;
      if (t0 + tau == TLEN-1) predz[(size_t)(b*4 + 0)*DM + c] = oln;
    }
  }
}

// ---------------- tiny_post: last token, residual base = cur[1023], fused LN -> predz[slot] ----
__global__ __launch_bounds__(128) void tiny_post_kernel(
    const float* __restrict__ ysbuf, const float* __restrict__ xibuf, const float* __restrict__ resgbuf,
    const float* __restrict__ Dp, const float* __restrict__ Wout, const float* __restrict__ cur,
    float* __restrict__ predz, const float* __restrict__ gamma, const float* __restrict__ beta, int slot)
{
  __shared__ float s_y[128];
  const int tid = threadIdx.x;
  const int b = blockIdx.x;
  size_t g = (size_t)(b*TLEN + TLEN-1)*DI + tid;
  s_y[tid] = (ysbuf[g] + xibuf[g]*Dp[tid]) * resgbuf[g];
  __syncthreads();
  if (tid < 64) {
    float a = 0.f;
    #pragma unroll 4
    for (int k = 0; k < 128; k++) a = fmaf(s_y[k], Wout[k*64 + tid], a);
    float val = cur[(size_t)(b*TLEN + TLEN-1)*DM + tid] + a;
    float sum = val;
    #pragma unroll
    for (int m = 1; m < 64; m <<= 1) sum += __shfl_xor(sum, m);
    float mean = sum * (1.f/64.f);
    float dv = val - mean;
    float vs = dv*dv;
    #pragma unroll
    for (int m = 1; m < 64; m <<= 1) vs += __shfl_xor(vs, m);
    float oln = dv * rsqrtf(vs*(1.f/64.f) + 1e-5f) * gamma[tid] + beta[tid];
    predz[(size_t)(b*4 + slot)*DM + tid] = oln;
  }
}

// ---------------- patch: [tiny_post of pass p-1 from ysbuf, base cur] + recompute pre(i0)
// tokens {p, p+1, p+2, 1023+p}. 8 blocks, 256 threads.
__global__ __launch_bounds__(256) void patch_kernel(
    int p, int do_tp,
    const float* __restrict__ ysbuf, const float* __restrict__ cur,
    const float* __restrict__ xi1, const float* __restrict__ resg1,
    const float* __restrict__ Dp1, const float* __restrict__ Wout1,
    const float* __restrict__ gamma, const float* __restrict__ beta,
    float* __restrict__ predz,
    float* __restrict__ xz0,
    const float* __restrict__ Win0, const float* __restrict__ Wconv0, const float* __restrict__ bconv0,
    const float* __restrict__ Wxp0, const float* __restrict__ Wdt0, const float* __restrict__ bdt0,
    float* __restrict__ xi0, float* __restrict__ resg0,
    float2* __restrict__ dd0, float* __restrict__ Bb0, float* __restrict__ Cb0)
{
  __shared__ float s_pz[64];
  __shared__ float s_y[128];
  __shared__ float s_new[256];
  __shared__ float s_xi[4][128];
  __shared__ float s_dtr[4][4];
  const int tid = threadIdx.x;
  const int b = blockIdx.x;
  const int gn = 1023 + p;

  if (do_tp) {
    if (tid < 128) {
      size_t g = (size_t)(b*TLEN + TLEN-1)*DI + tid;
      s_y[tid] = (ysbuf[g] + xi1[g]*Dp1[tid]) * resg1[g];
    }
    __syncthreads();
    if (tid < 64) {
      float a = 0.f;
      #pragma unroll 4
      for (int k = 0; k < 128; k++) a = fmaf(s_y[k], Wout1[k*64 + tid], a);
      float val = cur[(size_t)(b*TLEN + TLEN-1)*DM + tid] + a;
      float sum = val;
      #pragma unroll
      for (int m = 1; m < 64; m <<= 1) sum += __shfl_xor(sum, m);
      float mean = sum * (1.f/64.f);
      float dv = val - mean;
      float vs = dv*dv;
      #pragma unroll
      for (int m = 1; m < 64; m <<= 1) vs += __shfl_xor(vs, m);
      float oln = dv * rsqrtf(vs*(1.f/64.f) + 1e-5f) * gamma[tid] + beta[tid];
      predz[(size_t)(b*4 + p-1)*DM + tid] = oln;
      s_pz[tid] = oln;
    }
  } else {
    if (tid < 64) s_pz[tid] = predz[(size_t)(b*4 + p-1)*DM + tid];
  }
  __syncthreads();

  // phase 1: xz of the new token gn
  {
    float a = 0.f;
    #pragma unroll
    for (int k = 0; k < 64; k++) a = fmaf(s_pz[k], Win0[k*256 + tid], a);
    s_new[tid] = a;
  }
  __syncthreads();
  if (tid < 128) xz0[((size_t)b*GEXT + gn)*128 + tid] = s_new[tid];
  else           resg0[((size_t)b*GEXT + gn)*DI + (tid-128)] = siluf(s_new[tid]);

  // phase 2: conv + silu for 4 tokens x 128 ch
  #pragma unroll
  for (int jj = 0; jj < 2; jj++) {
    int job = tid + jj*256;
    int tok = job >> 7, d = job & 127;
    int g = (tok < 3) ? (p + tok) : gn;
    float a = bconv0[d];
    #pragma unroll
    for (int k = 0; k < 4; k++) {
      int row = g - 3 + k;
      float xv;
      if (tok < 3) xv = (row >= p) ? xz0[((size_t)b*GEXT + row)*128 + d] : 0.f;
      else         xv = (k < 3) ? xz0[((size_t)b*GEXT + row)*128 + d] : s_new[d];
      a = fmaf(xv, Wconv0[d*4 + k], a);
    }
    float xiv = siluf(a);
    s_xi[tok][d] = xiv;
    xi0[((size_t)b*GEXT + g)*DI + d] = xiv;
  }
  __syncthreads();

  // phase 3: xproj: 4 tokens x 68 cols = 272 jobs
  #pragma unroll
  for (int jj = 0; jj < 2; jj++) {
    int job = tid + jj*256;
    if (job < 272) {
      int tok = job / 68, c = job % 68;
      int g = (tok < 3) ? (p + tok) : gn;
      float a = 0.f;
      #pragma unroll 4
      for (int k = 0; k < 128; k++) a = fmaf(s_xi[tok][k], Wxp0[k*68 + c], a);
      if (c < 4)        s_dtr[tok][c] = a;
      else if (c < 36)  Bb0[((size_t)b*GEXT + g)*DS + (c - 4)]  = a;
      else              Cb0[((size_t)b*GEXT + g)*DS + (c - 36)] = a;
    }
  }
  __syncthreads();

  // phase 4: dt + dd
  #pragma unroll
  for (int jj = 0; jj < 2; jj++) {
    int job = tid + jj*256;
    int tok = job >> 7, d = job & 127;
    int g = (tok < 3) ? (p + tok) : gn;
    float a = bdt0[d];
    #pragma unroll
    for (int r = 0; r < 4; r++) a = fmaf(s_dtr[tok][r], Wdt0[r*128 + d], a);
    float dtv = softplusf(a);
    dd0[((size_t)b*GEXT + g)*DI + d] = make_float2(dtv, dtv * s_xi[tok][d]);
  }
}

extern "C" void kernel_launch(void* const* d_in, const int* in_sizes, int n_in,
                              void* d_out, int out_size, void* d_ws, size_t ws_size,
                              hipStream_t stream)
{
  (void)in_sizes; (void)n_in; (void)out_size; (void)ws_size;
  const float* x     = (const float*)d_in[0];
  const float* We1   = (const float*)d_in[1];
  const float* be1   = (const float*)d_in[2];
  const float* We2   = (const float*)d_in[3];
  const float* be2   = (const float*)d_in[4];
  const float* Wd1   = (const float*)d_in[5];
  const float* bd1   = (const float*)d_in[6];
  const float* Wd2   = (const float*)d_in[7];
  const float* bd2   = (const float*)d_in[8];
  const float* Win   = (const float*)d_in[9];
  const float* Wconv = (const float*)d_in[10];
  const float* bconv = (const float*)d_in[11];
  const float* Wxp   = (const float*)d_in[12];
  const float* Wdt   = (const float*)d_in[13];
  const float* bdt   = (const float*)d_in[14];
  const float* Alog  = (const float*)d_in[15];
  const float* Dp    = (const float*)d_in[16];
  const float* Wout  = (const float*)d_in[17];
  const float* gamma = (const float*)d_in[18];
  const float* beta  = (const float*)d_in[19];

  float* o      = (float*)d_out;
  float* x_rec  = o;                 // 8*1024*32
  float* x_dyn  = o + 262144;        // 8*1024*32
  float* x_pred = o + 524288;        // 8*4*32
  float* z      = o + 525312;        // 8*1024*64
  float* zdyn   = o + 1049600;       // 8*1024*64

  float* w     = (float*)d_ws;
  float* cur   = w;                            // 524288
  float* xi1   = cur  + 524288;                // 1048576
  float* resg1 = xi1  + 1048576;               // 1048576
  float2* dd1  = (float2*)(resg1 + 1048576);   // 2097152 floats
  float* Bb1   = resg1 + 1048576 + 2097152;    // 262144
  float* Cb1   = Bb1  + 262144;                // 262144
  float* ys    = Cb1  + 262144;                // 1048576
  float2* hc   = (float2*)(ys + 1048576);      // 1048576 floats
  float* predz = ys + 1048576 + 1048576;       // 2048
  float* xi0   = predz + 2048;                 // 1052672 (8*1028*128)
  float* resg0 = xi0  + 1052672;               // 1052672
  float2* dd0  = (float2*)(resg0 + 1052672);   // 2105344 floats
  float* Bb0   = resg0 + 1052672 + 2105344;    // 263168 (8*1028*32)
  float* Cb0   = Bb0  + 263168;                // 263168
  float* xz0   = Cb0  + 263168;                // 1052672

  const float* Win0 = Win,   *Win1 = Win + 64*256;
  const float* Wcv0 = Wconv, *Wcv1 = Wconv + 128*4;
  const float* bcv0 = bconv, *bcv1 = bconv + 128;
  const float* Wxp0 = Wxp,   *Wxp1 = Wxp + 128*68;
  const float* Wdt0 = Wdt,   *Wdt1 = Wdt + 4*128;
  const float* bdt0 = bdt,   *bdt1 = bdt + 128;
  const float* Al0  = Alog,  *Al1  = Alog + 128*32;
  const float* Dp0  = Dp,    *Dp1  = Dp + 128;
  const float* Wo0  = Wout,  *Wo1  = Wout + 128*64;

  // encoder + reconstruction decoder (fused)
  enc_xrec_kernel<<<dim3(512), dim3(256), 0, stream>>>(x, We1, be1, We2, be2, Wd1, bd1, Wd2, bd2, z, x_rec);

  // pre(i=0) ONCE over global z tokens, storing xz xi-half
  pre_kernel<<<dim3(1024), dim3(256), 0, stream>>>(cur, z, predz, 0,
                                                   Win0, Wcv0, bcv0, Wxp0, Wdt0, bdt0,
                                                   xi0, resg0, dd0, Bb0, Cb0, xz0, GEXT);

  for (int p = 0; p < 4; p++) {
    if (p >= 1) {
      patch_kernel<<<dim3(8), dim3(256), 0, stream>>>(p, (p >= 2) ? 1 : 0,
          ys, cur, xi1, resg1, Dp1, Wo1, gamma, beta, predz,
          xz0, Win0, Wcv0, bcv0, Wxp0, Wdt0, bdt0,
          xi0, resg0, dd0, Bb0, Cb0);
    }
    // ---- block i=0 (shared pre buffers, window at offset p) ----
    scan1_kernel<<<dim3(4096), dim3(128), 0, stream>>>(dd0, Bb0, Al0, hc, GEXT, p);
    scan3_kernel<<<dim3(4096), dim3(128), 0, stream>>>(dd0, Bb0, Cb0, Al0, hc, ys, -1, GEXT, p);
    post_kernel<<<dim3(1024), dim3(256), 0, stream>>>(ys, xi0, resg0, Dp0, Wo0,
                                                      z, predz, p, cur,
                                                      (float*)nullptr, (float*)nullptr,
                                                      (const float*)nullptr, (const float*)nullptr, 0,
                                                      GEXT, p);
    // ---- block i=1 (pass-local) ----
    pre_kernel<<<dim3(1024), dim3(256), 0, stream>>>(cur, (const float*)nullptr, (const float*)nullptr, 0,
                                                     Win1, Wcv1, bcv1, Wxp1, Wdt1, bdt1,
                                                     xi1, resg1, dd1, Bb1, Cb1, (float*)nullptr, TLEN);
    scan1_kernel<<<dim3(4096), dim3(128), 0, stream>>>(dd1, Bb1, Al1, hc, TLEN, 0);
    if (p == 0) {
      scan3_kernel<<<dim3(4096), dim3(128), 0, stream>>>(dd1, Bb1, Cb1, Al1, hc, ys, -1, TLEN, 0);
      post_kernel<<<dim3(1024), dim3(256), 0, stream>>>(ys, xi1, resg1, Dp1, Wo1,
                                                        (const float*)nullptr, (const float*)nullptr, 0, cur,
                                                        zdyn, predz, gamma, beta, 1, TLEN, 0);
    } else {
      // last chunk only -> ys tokens 960..1023 (token 1023 consumed by next patch / final tiny_post)
      scan3_kernel<<<dim3(256), dim3(128), 0, stream>>>(dd1, Bb1, Cb1, Al1, hc, ys, 15, TLEN, 0);
    }
  }

  // finish: predz[3] from pass-3 block-1 ys
  tiny_post_kernel<<<dim3(8), dim3(128), 0, stream>>>(ys, xi1, resg1, Dp1, Wo1, cur,
                                                      predz, gamma, beta, 3);

  // x_dyn = dec(zdyn) + x_pred = dec(predz)
  dec2_kernel<<<dim3(514), dim3(256), 0, stream>>>(zdyn, predz, Wd1, bd1, Wd2, bd2, x_dyn, x_pred);
}